// Round 1
// baseline (1012.589 us; speedup 1.0000x reference)
//
#include <hip/hip_runtime.h>
#include <math.h>

#define BB 8
#define CC 512
#define SS 1024
#define NHH 8
#define HDD 64

// ---------- block-wide sum over 256 threads (4 waves) ----------
__device__ __forceinline__ float block_reduce_sum(float v) {
  __shared__ float sm[4];
  #pragma unroll
  for (int o = 32; o > 0; o >>= 1) v += __shfl_down(v, o, 64);
  if ((threadIdx.x & 63) == 0) sm[threadIdx.x >> 6] = v;
  __syncthreads();
  float r = (sm[0] + sm[1]) + (sm[2] + sm[3]);
  __syncthreads();  // protect sm for a second call
  return r;
}

// ---------- batched 2D transpose: in (B, d1, d2) -> out (B, d2, d1) ----------
__global__ __launch_bounds__(256) void transpose_k(const float* __restrict__ in,
                                                   float* __restrict__ out,
                                                   int d1, int d2) {
  __shared__ float tile[32][33];
  int b = blockIdx.z;
  int j0 = blockIdx.x * 32;  // over d2
  int i0 = blockIdx.y * 32;  // over d1
  const float* inb = in + (size_t)b * d1 * d2;
  float* outb = out + (size_t)b * d1 * d2;
  int tx = threadIdx.x, ty = threadIdx.y;  // (32, 8)
  #pragma unroll
  for (int i = ty; i < 32; i += 8)
    tile[i][tx] = inb[(size_t)(i0 + i) * d2 + j0 + tx];
  __syncthreads();
  #pragma unroll
  for (int i = ty; i < 32; i += 8)
    outb[(size_t)(j0 + i) * d1 + i0 + tx] = tile[tx][i];
}

// ---------- LayerNorm over last dim (C=512); one block per row ----------
__global__ __launch_bounds__(256) void ln_k(const float* __restrict__ in,
                                            const float* __restrict__ g,
                                            const float* __restrict__ be,
                                            float* __restrict__ out) {
  size_t row = blockIdx.x;
  const float* r = in + row * CC;
  int t = threadIdx.x;
  float v0 = r[t], v1 = r[t + 256];
  float s = block_reduce_sum(v0 + v1);
  float mu = s * (1.0f / CC);
  float d0 = v0 - mu, d1 = v1 - mu;
  float vs = block_reduce_sum(d0 * d0 + d1 * d1);
  float rstd = rsqrtf(vs * (1.0f / CC) + 1e-5f);
  out[row * CC + t]        = d0 * rstd * g[t] + be[t];
  out[row * CC + t + 256]  = d1 * rstd * g[t + 256] + be[t + 256];
}

// ---------- GEMM: out[M=8192, N=512] = A[M,512] @ W + bias (+gelu) (+resid) ----
// qkv_layout=1: W is (NH, K, 64), column j=(h*64+d) -> W[h*K*64 + k*64 + d]
// qkv_layout=0: W is row-major (K, N)
__global__ __launch_bounds__(256) void gemm_k(const float* __restrict__ A,
                                              const float* __restrict__ W,
                                              const float* __restrict__ bias,
                                              const float* __restrict__ resid,
                                              float* __restrict__ out,
                                              int qkv_layout, int act_gelu) {
  const int N = 512, K = 512;
  __shared__ float As[16][65];  // [kk][m]
  __shared__ float Bs[16][65];  // [kk][n]
  int n0 = blockIdx.x * 64, m0 = blockIdx.y * 64;
  int tid = threadIdx.x;
  int tx = tid & 15, ty = tid >> 4;
  int lm = tid >> 2, lk = (tid & 3) * 4;   // A loader: 64 rows x 16 k
  int bk = tid >> 4, bn = (tid & 15) * 4;  // B loader: 16 k x 64 n
  const float* Aload = A + (size_t)(m0 + lm) * K + lk;
  const float* Bload;
  size_t bstep;
  if (qkv_layout) {
    Bload = W + (size_t)(n0 >> 6) * K * 64 + (size_t)bk * 64 + bn;
    bstep = (size_t)16 * 64;
  } else {
    Bload = W + (size_t)bk * N + n0 + bn;
    bstep = (size_t)16 * N;
  }
  float acc[4][4] = {};
  for (int k0 = 0; k0 < K; k0 += 16) {
    float4 av = *(const float4*)(Aload + k0);
    float4 bv = *(const float4*)Bload;
    Bload += bstep;
    __syncthreads();
    As[lk + 0][lm] = av.x; As[lk + 1][lm] = av.y;
    As[lk + 2][lm] = av.z; As[lk + 3][lm] = av.w;
    Bs[bk][bn + 0] = bv.x; Bs[bk][bn + 1] = bv.y;
    Bs[bk][bn + 2] = bv.z; Bs[bk][bn + 3] = bv.w;
    __syncthreads();
    #pragma unroll
    for (int kk = 0; kk < 16; ++kk) {
      float a[4], bb[4];
      #pragma unroll
      for (int i = 0; i < 4; ++i) a[i] = As[kk][ty * 4 + i];
      #pragma unroll
      for (int j = 0; j < 4; ++j) bb[j] = Bs[kk][tx * 4 + j];
      #pragma unroll
      for (int i = 0; i < 4; ++i)
        #pragma unroll
        for (int j = 0; j < 4; ++j)
          acc[i][j] += a[i] * bb[j];
    }
  }
  #pragma unroll
  for (int i = 0; i < 4; ++i) {
    int m = m0 + ty * 4 + i;
    #pragma unroll
    for (int j = 0; j < 4; ++j) {
      int n = n0 + tx * 4 + j;
      float v = acc[i][j] + bias[n];
      if (act_gelu) v = 0.5f * v * (1.0f + erff(v * 0.70710678118654752f));
      if (resid) v += resid[(size_t)m * N + n];
      out[(size_t)m * N + n] = v;
    }
  }
}

// ---------- flash attention: block = (b, h, 64-query tile) ----------
// q,k,v,o layout: (B, S, NH, HD) flat; scale = 1/sqrt(C) per reference
__global__ __launch_bounds__(256) void attn_k(const float* __restrict__ Q,
                                              const float* __restrict__ Kp,
                                              const float* __restrict__ V,
                                              float* __restrict__ O) {
  __shared__ float Qs[64][65];
  __shared__ float Ks[64][65];  // reused as P after scores
  __shared__ float Vs[64][65];
  int q0 = blockIdx.x * 64;
  int h = blockIdx.y;
  int b = blockIdx.z;
  size_t base = (size_t)b * SS * 512 + (size_t)h * 64;
  int tid = threadIdx.x;
  int tx = tid & 15, ty = tid >> 4;
  int lr = tid >> 2, ld = (tid & 3) * 16;
  {
    const float* src = Q + base + (size_t)(q0 + lr) * 512 + ld;
    #pragma unroll
    for (int u = 0; u < 16; ++u) Qs[lr][ld + u] = src[u];
  }
  float mrow[4], lrow[4], oacc[4][4];
  #pragma unroll
  for (int i = 0; i < 4; ++i) {
    mrow[i] = -1e30f; lrow[i] = 0.0f;
    #pragma unroll
    for (int j = 0; j < 4; ++j) oacc[i][j] = 0.0f;
  }
  const float scale = 0.044194173824159216f;  // 1/sqrt(512)
  for (int kt = 0; kt < SS; kt += 64) {
    __syncthreads();  // previous PV done: safe to overwrite Ks/Vs
    {
      const float* ks = Kp + base + (size_t)(kt + lr) * 512 + ld;
      const float* vs = V + base + (size_t)(kt + lr) * 512 + ld;
      #pragma unroll
      for (int u = 0; u < 16; ++u) { Ks[lr][ld + u] = ks[u]; Vs[lr][ld + u] = vs[u]; }
    }
    __syncthreads();  // tiles visible (covers Qs too on first iter)
    float sc[4][4] = {};
    #pragma unroll 4
    for (int d = 0; d < 64; ++d) {
      float a[4], bb[4];
      #pragma unroll
      for (int i = 0; i < 4; ++i) a[i] = Qs[ty * 4 + i][d];
      #pragma unroll
      for (int j = 0; j < 4; ++j) bb[j] = Ks[tx * 4 + j][d];
      #pragma unroll
      for (int i = 0; i < 4; ++i)
        #pragma unroll
        for (int j = 0; j < 4; ++j)
          sc[i][j] += a[i] * bb[j];
    }
    #pragma unroll
    for (int i = 0; i < 4; ++i) {
      #pragma unroll
      for (int j = 0; j < 4; ++j) sc[i][j] *= scale;
      float mt = fmaxf(fmaxf(sc[i][0], sc[i][1]), fmaxf(sc[i][2], sc[i][3]));
      #pragma unroll
      for (int msk = 1; msk < 16; msk <<= 1) mt = fmaxf(mt, __shfl_xor(mt, msk, 64));
      float mn = fmaxf(mrow[i], mt);
      float alpha = __expf(mrow[i] - mn);
      mrow[i] = mn;
      float ls = 0.0f;
      #pragma unroll
      for (int j = 0; j < 4; ++j) { sc[i][j] = __expf(sc[i][j] - mn); ls += sc[i][j]; }
      #pragma unroll
      for (int msk = 1; msk < 16; msk <<= 1) ls += __shfl_xor(ls, msk, 64);
      lrow[i] = lrow[i] * alpha + ls;
      #pragma unroll
      for (int j = 0; j < 4; ++j) oacc[i][j] *= alpha;
    }
    __syncthreads();  // all Ks reads (scores) done -> safe to overwrite with P
    #pragma unroll
    for (int i = 0; i < 4; ++i)
      #pragma unroll
      for (int j = 0; j < 4; ++j)
        Ks[ty * 4 + i][tx * 4 + j] = sc[i][j];
    __syncthreads();  // P visible
    #pragma unroll 4
    for (int c = 0; c < 64; ++c) {
      float p[4], vv[4];
      #pragma unroll
      for (int i = 0; i < 4; ++i) p[i] = Ks[ty * 4 + i][c];
      #pragma unroll
      for (int j = 0; j < 4; ++j) vv[j] = Vs[c][tx * 4 + j];
      #pragma unroll
      for (int i = 0; i < 4; ++i)
        #pragma unroll
        for (int j = 0; j < 4; ++j)
          oacc[i][j] += p[i] * vv[j];
    }
  }
  #pragma unroll
  for (int i = 0; i < 4; ++i) {
    float inv = 1.0f / lrow[i];
    #pragma unroll
    for (int j = 0; j < 4; ++j)
      O[base + (size_t)(q0 + ty * 4 + i) * 512 + tx * 4 + j] = oacc[i][j] * inv;
  }
}

extern "C" void kernel_launch(void* const* d_in, const int* in_sizes, int n_in,
                              void* d_out, int out_size, void* d_ws, size_t ws_size,
                              hipStream_t stream) {
  const float* x    = (const float*)d_in[0];
  // d_in[1] = t : unused by the reference
  const float* K_W  = (const float*)d_in[2];
  const float* K_b  = (const float*)d_in[3];
  const float* Q_W  = (const float*)d_in[4];
  const float* Q_b  = (const float*)d_in[5];
  const float* V_W  = (const float*)d_in[6];
  const float* V_b  = (const float*)d_in[7];
  const float* O_W  = (const float*)d_in[8];
  const float* O_b  = (const float*)d_in[9];
  const float* ln1g = (const float*)d_in[10];
  const float* ln1b = (const float*)d_in[11];
  const float* ln2g = (const float*)d_in[12];
  const float* ln2b = (const float*)d_in[13];
  const float* W1   = (const float*)d_in[14];
  const float* b1   = (const float*)d_in[15];
  const float* W2   = (const float*)d_in[16];
  const float* b2   = (const float*)d_in[17];
  float* out = (float*)d_out;

  const size_t SZ = (size_t)BB * SS * CC;  // 4,194,304 elements = 16 MB
  float* ws   = (float*)d_ws;
  float* buf0 = ws;            // res -> o -> ln2out
  float* bufq = ws + SZ;       // q -> h (post-GELU)
  float* bufk = ws + 2 * SZ;   // k -> out2
  float* bufv = ws + 3 * SZ;   // v
  float* bufx = ws + 4 * SZ;   // xs -> out1 (residual stream)

  dim3 tb(32, 8);
  // x (B,C,S) -> xs (B,S,C)
  transpose_k<<<dim3(SS / 32, CC / 32, BB), tb, 0, stream>>>(x, bufx, CC, SS);
  // LN1
  ln_k<<<BB * SS, 256, 0, stream>>>(bufx, ln1g, ln1b, buf0);
  // QKV projections
  dim3 gg(512 / 64, (BB * SS) / 64);
  gemm_k<<<gg, 256, 0, stream>>>(buf0, Q_W, Q_b, nullptr, bufq, 1, 0);
  gemm_k<<<gg, 256, 0, stream>>>(buf0, K_W, K_b, nullptr, bufk, 1, 0);
  gemm_k<<<gg, 256, 0, stream>>>(buf0, V_W, V_b, nullptr, bufv, 1, 0);
  // attention -> o in buf0
  attn_k<<<dim3(SS / 64, NHH, BB), 256, 0, stream>>>(bufq, bufk, bufv, buf0);
  // O projection + residual(xs): out1 -> bufx (in-place residual read)
  gemm_k<<<gg, 256, 0, stream>>>(buf0, O_W, O_b, bufx, bufx, 0, 0);
  // LN2
  ln_k<<<BB * SS, 256, 0, stream>>>(bufx, ln2g, ln2b, buf0);
  // MLP
  gemm_k<<<gg, 256, 0, stream>>>(buf0, W1, b1, nullptr, bufq, 0, 1);
  gemm_k<<<gg, 256, 0, stream>>>(bufq, W2, b2, bufx, bufk, 0, 0);
  // out2 (B,S,C) -> (B,C,S)
  transpose_k<<<dim3(CC / 32, SS / 32, BB), tb, 0, stream>>>(bufk, out, SS, CC);
}

// Round 3
// 385.393 us; speedup vs baseline: 2.6274x; 2.6274x over previous
//
#include <hip/hip_runtime.h>
#include <math.h>

#define BB 8
#define CC 512
#define SS 1024
#define NHH 8
#define HDD 64
#define KD 512

typedef __attribute__((ext_vector_type(8))) short short8;
typedef __attribute__((ext_vector_type(4))) float f32x4;

__device__ __forceinline__ unsigned short f2bf(float x) {
  union { float f; unsigned int u; } c; c.f = x;
  unsigned int r = (c.u + 0x7FFFu + ((c.u >> 16) & 1u)) >> 16;
  return (unsigned short)r;
}
__device__ __forceinline__ float b2f(unsigned short h) {
  union { unsigned int u; float f; } c; c.u = ((unsigned int)h) << 16; return c.f;
}

#define GLD_LDS(gp, lp) __builtin_amdgcn_global_load_lds( \
    (const __attribute__((address_space(1))) void*)(gp),  \
    (__attribute__((address_space(3))) void*)(lp), 16, 0, 0)

// ---------- block-wide sum over 256 threads (4 waves) ----------
__device__ __forceinline__ float block_reduce_sum(float v) {
  __shared__ float sm[4];
  #pragma unroll
  for (int o = 32; o > 0; o >>= 1) v += __shfl_down(v, o, 64);
  if ((threadIdx.x & 63) == 0) sm[threadIdx.x >> 6] = v;
  __syncthreads();
  float r = (sm[0] + sm[1]) + (sm[2] + sm[3]);
  __syncthreads();
  return r;
}

// ---------- batched 2D transpose: in (B, d1, d2) -> out (B, d2, d1), fp32 ----
__global__ __launch_bounds__(256) void transpose_k(const float* __restrict__ in,
                                                   float* __restrict__ out,
                                                   int d1, int d2) {
  __shared__ float tile[32][33];
  int b = blockIdx.z;
  int j0 = blockIdx.x * 32;
  int i0 = blockIdx.y * 32;
  const float* inb = in + (size_t)b * d1 * d2;
  float* outb = out + (size_t)b * d1 * d2;
  int tx = threadIdx.x, ty = threadIdx.y;  // (32, 8)
  #pragma unroll
  for (int i = ty; i < 32; i += 8)
    tile[i][tx] = inb[(size_t)(i0 + i) * d2 + j0 + tx];
  __syncthreads();
  #pragma unroll
  for (int i = ty; i < 32; i += 8)
    outb[(size_t)(j0 + i) * d1 + i0 + tx] = tile[tx][i];
}

// ---------- LayerNorm (C=512) -> bf16 hi (+ optional lo plane) ---------------
__global__ __launch_bounds__(256) void ln_bf16_k(const float* __restrict__ in,
                                                 const float* __restrict__ g,
                                                 const float* __restrict__ be,
                                                 unsigned short* __restrict__ outh,
                                                 unsigned short* __restrict__ outl) {
  size_t row = blockIdx.x;
  const float* r = in + row * CC;
  int t = threadIdx.x;
  float v0 = r[t], v1 = r[t + 256];
  float s = block_reduce_sum(v0 + v1);
  float mu = s * (1.0f / CC);
  float d0 = v0 - mu, d1 = v1 - mu;
  float vs = block_reduce_sum(d0 * d0 + d1 * d1);
  float rstd = rsqrtf(vs * (1.0f / CC) + 1e-5f);
  float y0 = d0 * rstd * g[t] + be[t];
  float y1 = d1 * rstd * g[t + 256] + be[t + 256];
  unsigned short h0 = f2bf(y0), h1 = f2bf(y1);
  outh[row * CC + t]       = h0;
  outh[row * CC + t + 256] = h1;
  if (outl) {
    outl[row * CC + t]       = f2bf(y0 - b2f(h0));
    outl[row * CC + t + 256] = f2bf(y1 - b2f(h1));
  }
}

// ---------- weight convert: fp32 -> bf16 hi/lo B^T (N,K) ---------------------
// 48 panels: 0-7 QW, 8-15 KW, 16-23 VW (hi+lo), 24-31 OW (hi+lo),
//            32-39 W1 (hi), 40-47 W2 (hi)
__global__ __launch_bounds__(256) void convert_weights(
    const float* __restrict__ QW, const float* __restrict__ KW,
    const float* __restrict__ VW, const float* __restrict__ OW,
    const float* __restrict__ W1, const float* __restrict__ W2,
    const float* __restrict__ Qb, const float* __restrict__ Kb,
    const float* __restrict__ Vb,
    unsigned short* __restrict__ BtQKVh, unsigned short* __restrict__ BtQKVl,
    unsigned short* __restrict__ BtOh, unsigned short* __restrict__ BtOl,
    unsigned short* __restrict__ BtW1h, unsigned short* __restrict__ BtW2h,
    float* __restrict__ qkvb) {
  __shared__ float tile[32][33];
  const int p = blockIdx.z, wsel = p >> 3, sub = p & 7;
  const int k0 = blockIdx.x * 32, d0 = blockIdx.y * 32;
  const int tx = threadIdx.x, ty = threadIdx.y;
  const float* w; int rs; unsigned short *dh, *dl; int nbase;
  switch (wsel) {
    case 0:  w = QW + sub * 32768; rs = 64;  dh = BtQKVh; dl = BtQKVl; nbase = sub * 64;        break;
    case 1:  w = KW + sub * 32768; rs = 64;  dh = BtQKVh; dl = BtQKVl; nbase = 512 + sub * 64;  break;
    case 2:  w = VW + sub * 32768; rs = 64;  dh = BtQKVh; dl = BtQKVl; nbase = 1024 + sub * 64; break;
    case 3:  w = OW + sub * 64;    rs = 512; dh = BtOh;   dl = BtOl;   nbase = sub * 64;        break;
    case 4:  w = W1 + sub * 64;    rs = 512; dh = BtW1h;  dl = nullptr; nbase = sub * 64;       break;
    default: w = W2 + sub * 64;    rs = 512; dh = BtW2h;  dl = nullptr; nbase = sub * 64;       break;
  }
  for (int i = ty; i < 32; i += 8)
    tile[i][tx] = w[(size_t)(k0 + i) * rs + d0 + tx];
  __syncthreads();
  for (int i = ty; i < 32; i += 8) {
    float f = tile[tx][i];
    unsigned short h = f2bf(f);
    size_t idx = (size_t)(nbase + d0 + i) * KD + k0 + tx;
    dh[idx] = h;
    if (dl) dl[idx] = f2bf(f - b2f(h));
  }
  if (p == 0 && blockIdx.x == 0 && blockIdx.y == 0) {
    int t = ty * 32 + tx;
    for (int i = t; i < 1536; i += 256)
      qkvb[i] = i < 512 ? Qb[i] : (i < 1024 ? Kb[i - 512] : Vb[i - 1024]);
  }
}

// ---------- MFMA GEMM: out[M, N] = A[M,512] @ Bt[N,512]^T + bias -------------
// SPLIT: A,B given as hi/lo bf16 planes, 3 MFMAs (hh+hl+lh) per product.
// OUTMODE: 0 = fp32, 1 = bf16 hi, 2 = bf16 hi+lo
template<int SPLIT, int GELU, int OUTMODE, int RESID>
__global__ __launch_bounds__(256) void gemm_mfma(
    const unsigned short* __restrict__ Ah, const unsigned short* __restrict__ Al,
    const unsigned short* __restrict__ Bh, const unsigned short* __restrict__ Bl,
    const float* __restrict__ bias, const float* __restrict__ resid,
    unsigned short* __restrict__ outh, unsigned short* __restrict__ outl,
    float* __restrict__ outf, int ldc) {
  constexpr int NP = SPLIT ? 2 : 1;
  __shared__ __align__(16) unsigned short As[NP * 128 * 32];
  __shared__ __align__(16) unsigned short Bs[NP * 128 * 32];
  const int tid = threadIdx.x;
  const int w = tid >> 6, l = tid & 63, quad = l >> 4, lm = l & 15;
  const int n0 = blockIdx.x * 128, m0 = blockIdx.y * 128;
  const int wm = (w >> 1) * 64, wn = (w & 1) * 64;
  const int srow = tid >> 2, sch = (tid & 3) * 8;
  const unsigned short* Agh = Ah + (size_t)(m0 + srow) * KD + sch;
  const unsigned short* Bgh = Bh + (size_t)(n0 + srow) * KD + sch;
  const unsigned short* Agl = SPLIT ? Al + (size_t)(m0 + srow) * KD + sch : nullptr;
  const unsigned short* Bgl = SPLIT ? Bl + (size_t)(n0 + srow) * KD + sch : nullptr;
  unsigned short* Aswh = As + w * 512;
  unsigned short* Bswh = Bs + w * 512;
  unsigned short* Aswl = As + 4096 + w * 512;
  unsigned short* Bswl = Bs + 4096 + w * 512;
  const f32x4 fzero = {0.f, 0.f, 0.f, 0.f};
  f32x4 acc[4][4];
  #pragma unroll
  for (int i = 0; i < 4; ++i)
    #pragma unroll
    for (int j = 0; j < 4; ++j) acc[i][j] = fzero;
  for (int k0 = 0; k0 < KD; k0 += 32) {
    __syncthreads();
    GLD_LDS(Agh + k0, Aswh);
    GLD_LDS(Agh + k0 + 64 * KD, Aswh + 2048);
    GLD_LDS(Bgh + k0, Bswh);
    GLD_LDS(Bgh + k0 + 64 * KD, Bswh + 2048);
    if constexpr (SPLIT) {
      GLD_LDS(Agl + k0, Aswl);
      GLD_LDS(Agl + k0 + 64 * KD, Aswl + 2048);
      GLD_LDS(Bgl + k0, Bswl);
      GLD_LDS(Bgl + k0 + 64 * KD, Bswl + 2048);
    }
    __syncthreads();
    short8 afh[4], bfh[4], afl[4], bfl[4];
    #pragma unroll
    for (int i = 0; i < 4; ++i)
      afh[i] = *(const short8*)(As + (wm + i * 16 + lm) * 32 + quad * 8);
    #pragma unroll
    for (int j = 0; j < 4; ++j)
      bfh[j] = *(const short8*)(Bs + (wn + j * 16 + lm) * 32 + quad * 8);
    if constexpr (SPLIT) {
      #pragma unroll
      for (int i = 0; i < 4; ++i)
        afl[i] = *(const short8*)(As + 4096 + (wm + i * 16 + lm) * 32 + quad * 8);
      #pragma unroll
      for (int j = 0; j < 4; ++j)
        bfl[j] = *(const short8*)(Bs + 4096 + (wn + j * 16 + lm) * 32 + quad * 8);
    }
    #pragma unroll
    for (int i = 0; i < 4; ++i)
      #pragma unroll
      for (int j = 0; j < 4; ++j) {
        f32x4 t = acc[i][j];
        t = __builtin_amdgcn_mfma_f32_16x16x32_bf16(afh[i], bfh[j], t, 0, 0, 0);
        if constexpr (SPLIT) {
          t = __builtin_amdgcn_mfma_f32_16x16x32_bf16(afh[i], bfl[j], t, 0, 0, 0);
          t = __builtin_amdgcn_mfma_f32_16x16x32_bf16(afl[i], bfh[j], t, 0, 0, 0);
        }
        acc[i][j] = t;
      }
  }
  #pragma unroll
  for (int i = 0; i < 4; ++i) {
    const int row = m0 + wm + i * 16 + quad * 4;
    #pragma unroll
    for (int j = 0; j < 4; ++j) {
      const int col = n0 + wn + j * 16 + lm;
      const float bv = bias[col];
      #pragma unroll
      for (int r = 0; r < 4; ++r) {
        float x = acc[i][j][r] + bv;
        if (GELU) x = 0.5f * x * (1.0f + erff(x * 0.70710678118654752f));
        if (RESID) x += resid[(size_t)(row + r) * CC + col];
        const size_t oi = (size_t)(row + r) * ldc + col;
        if (OUTMODE == 0) {
          outf[oi] = x;
        } else if (OUTMODE == 1) {
          outh[oi] = f2bf(x);
        } else {
          unsigned short h = f2bf(x);
          outh[oi] = h;
          outl[oi] = f2bf(x - b2f(h));
        }
      }
    }
  }
}

// ---------- flash attention, split-bf16 MFMA ---------------------------------
// QKV hi/lo: (B, S, 1536) bf16 [Q | K | V]; O hi/lo: (B, S, 512) bf16
__global__ __launch_bounds__(256) void attn_mfma(
    const unsigned short* __restrict__ QKVh, const unsigned short* __restrict__ QKVl,
    unsigned short* __restrict__ Oh, unsigned short* __restrict__ Ol) {
  __shared__ __align__(16) unsigned short Ksh[64 * 72], Ksl[64 * 72];
  __shared__ __align__(16) unsigned short Vth[64 * 72], Vtl[64 * 72];
  __shared__ __align__(16) unsigned short Psh[4 * 16 * 72], Psl[4 * 16 * 72];
  const int q0 = blockIdx.x * 64, h = blockIdx.y, b = blockIdx.z;
  const int tid = threadIdx.x, w = tid >> 6, l = tid & 63, quad = l >> 4, lm = l & 15;
  const int LDQ = 3 * CC;
  const size_t bbase = (size_t)b * SS * LDQ;
  const int srow = tid >> 2, sch = (tid & 3) * 8;
  // Q fragments in registers (A-layout: m=lm, k=st*32+quad*8)
  short8 qh[2], ql[2];
  {
    const unsigned short* qb =
        QKVh + bbase + (size_t)(q0 + w * 16 + lm) * LDQ + h * 64 + quad * 8;
    const unsigned short* qbl =
        QKVl + bbase + (size_t)(q0 + w * 16 + lm) * LDQ + h * 64 + quad * 8;
    qh[0] = *(const short8*)qb;        qh[1] = *(const short8*)(qb + 32);
    ql[0] = *(const short8*)qbl;       ql[1] = *(const short8*)(qbl + 32);
  }
  const f32x4 fzero = {0.f, 0.f, 0.f, 0.f};
  float mrow[4], lrow[4];
  f32x4 oacc[4];
  #pragma unroll
  for (int r = 0; r < 4; ++r) { mrow[r] = -1e30f; lrow[r] = 0.f; }
  #pragma unroll
  for (int j = 0; j < 4; ++j) oacc[j] = fzero;
  const float scale = 0.044194173824159216f;  // 1/sqrt(512)
  unsigned short* Pwh = Psh + w * (16 * 72);
  unsigned short* Pwl = Psl + w * (16 * 72);
  for (int kt = 0; kt < SS; kt += 64) {
    __syncthreads();  // previous tile fully consumed
    {
      const size_t ko = bbase + (size_t)(kt + srow) * LDQ + CC + h * 64 + sch;
      *(short8*)(Ksh + srow * 72 + sch)      = *(const short8*)(QKVh + ko);
      *(short8*)(Ksh + srow * 72 + sch + 32) = *(const short8*)(QKVh + ko + 32);
      *(short8*)(Ksl + srow * 72 + sch)      = *(const short8*)(QKVl + ko);
      *(short8*)(Ksl + srow * 72 + sch + 32) = *(const short8*)(QKVl + ko + 32);
      #pragma unroll
      for (int pass = 0; pass < 2; ++pass) {
        const int c = w + pass * 4;
        const size_t vo = bbase + (size_t)(kt + l) * LDQ + 2 * CC + h * 64 + c * 8;
        short8 vh8 = *(const short8*)(QKVh + vo);
        short8 vl8 = *(const short8*)(QKVl + vo);
        #pragma unroll
        for (int u = 0; u < 8; ++u) {
          Vth[(c * 8 + u) * 72 + l] = (unsigned short)vh8[u];
          Vtl[(c * 8 + u) * 72 + l] = (unsigned short)vl8[u];
        }
      }
    }
    __syncthreads();
    // scores (bf16x3): wave w's 16 q-rows vs 64 keys
    f32x4 sc[4];
    #pragma unroll
    for (int j = 0; j < 4; ++j) sc[j] = fzero;
    #pragma unroll
    for (int st = 0; st < 2; ++st) {
      #pragma unroll
      for (int j = 0; j < 4; ++j) {
        short8 kh = *(const short8*)(Ksh + (j * 16 + lm) * 72 + st * 32 + quad * 8);
        short8 kl = *(const short8*)(Ksl + (j * 16 + lm) * 72 + st * 32 + quad * 8);
        f32x4 t = sc[j];
        t = __builtin_amdgcn_mfma_f32_16x16x32_bf16(qh[st], kh, t, 0, 0, 0);
        t = __builtin_amdgcn_mfma_f32_16x16x32_bf16(qh[st], kl, t, 0, 0, 0);
        t = __builtin_amdgcn_mfma_f32_16x16x32_bf16(ql[st], kh, t, 0, 0, 0);
        sc[j] = t;
      }
    }
    #pragma unroll
    for (int j = 0; j < 4; ++j) sc[j] *= scale;
    // online softmax (C-layout: col=lm, row=quad*4+r)
    #pragma unroll
    for (int r = 0; r < 4; ++r) {
      float mt = fmaxf(fmaxf(sc[0][r], sc[1][r]), fmaxf(sc[2][r], sc[3][r]));
      #pragma unroll
      for (int mask = 1; mask < 16; mask <<= 1) mt = fmaxf(mt, __shfl_xor(mt, mask, 64));
      const float mn = fmaxf(mrow[r], mt);
      const float alpha = __expf(mrow[r] - mn);
      mrow[r] = mn;
      float ls = 0.f;
      #pragma unroll
      for (int j = 0; j < 4; ++j) {
        const float p = __expf(sc[j][r] - mn);
        sc[j][r] = p;
        ls += p;
      }
      #pragma unroll
      for (int mask = 1; mask < 16; mask <<= 1) ls += __shfl_xor(ls, mask, 64);
      lrow[r] = lrow[r] * alpha + ls;
      #pragma unroll
      for (int j = 0; j < 4; ++j) oacc[j][r] *= alpha;
    }
    // P hi/lo -> per-wave LDS (A-layout)
    #pragma unroll
    for (int r = 0; r < 4; ++r)
      #pragma unroll
      for (int j = 0; j < 4; ++j) {
        const float p = sc[j][r];
        unsigned short ph = f2bf(p);
        Pwh[(quad * 4 + r) * 72 + j * 16 + lm] = ph;
        Pwl[(quad * 4 + r) * 72 + j * 16 + lm] = f2bf(p - b2f(ph));
      }
    __syncthreads();
    // PV (bf16x3)
    #pragma unroll
    for (int st = 0; st < 2; ++st) {
      short8 aph = *(const short8*)(Pwh + lm * 72 + st * 32 + quad * 8);
      short8 apl = *(const short8*)(Pwl + lm * 72 + st * 32 + quad * 8);
      #pragma unroll
      for (int j = 0; j < 4; ++j) {
        short8 vh = *(const short8*)(Vth + (j * 16 + lm) * 72 + st * 32 + quad * 8);
        short8 vl = *(const short8*)(Vtl + (j * 16 + lm) * 72 + st * 32 + quad * 8);
        f32x4 t = oacc[j];
        t = __builtin_amdgcn_mfma_f32_16x16x32_bf16(aph, vh, t, 0, 0, 0);
        t = __builtin_amdgcn_mfma_f32_16x16x32_bf16(aph, vl, t, 0, 0, 0);
        t = __builtin_amdgcn_mfma_f32_16x16x32_bf16(apl, vh, t, 0, 0, 0);
        oacc[j] = t;
      }
    }
  }
  float inv[4];
  #pragma unroll
  for (int r = 0; r < 4; ++r) inv[r] = 1.f / lrow[r];
  const size_t obase =
      (size_t)b * SS * CC + (size_t)(q0 + w * 16 + quad * 4) * CC + h * 64 + lm;
  #pragma unroll
  for (int j = 0; j < 4; ++j)
    #pragma unroll
    for (int r = 0; r < 4; ++r) {
      const float val = oacc[j][r] * inv[r];
      unsigned short hv = f2bf(val);
      Oh[obase + (size_t)r * CC + j * 16] = hv;
      Ol[obase + (size_t)r * CC + j * 16] = f2bf(val - b2f(hv));
    }
}

extern "C" void kernel_launch(void* const* d_in, const int* in_sizes, int n_in,
                              void* d_out, int out_size, void* d_ws, size_t ws_size,
                              hipStream_t stream) {
  const float* x    = (const float*)d_in[0];
  const float* K_W  = (const float*)d_in[2];
  const float* K_b  = (const float*)d_in[3];
  const float* Q_W  = (const float*)d_in[4];
  const float* Q_b  = (const float*)d_in[5];
  const float* V_W  = (const float*)d_in[6];
  const float* V_b  = (const float*)d_in[7];
  const float* O_W  = (const float*)d_in[8];
  const float* O_b  = (const float*)d_in[9];
  const float* ln1g = (const float*)d_in[10];
  const float* ln1b = (const float*)d_in[11];
  const float* ln2g = (const float*)d_in[12];
  const float* ln2b = (const float*)d_in[13];
  const float* W1   = (const float*)d_in[14];
  const float* b1   = (const float*)d_in[15];
  const float* W2   = (const float*)d_in[16];
  const float* b2   = (const float*)d_in[17];
  float* out = (float*)d_out;

  unsigned char* ws = (unsigned char*)d_ws;
  const size_t MB = 1u << 20;
  float* bufx           = (float*)(ws);                  // xs fp32, 16MB, live->O-proj
  unsigned short* qkvh  = (unsigned short*)(ws + 16 * MB);   // 24MB
  unsigned short* qkvl  = (unsigned short*)(ws + 40 * MB);   // 24MB
  unsigned short* ln1h  = (unsigned short*)(ws + 64 * MB);   // 8MB
  unsigned short* ln1l  = (unsigned short*)(ws + 72 * MB);   // 8MB
  unsigned short* oh    = ln1h;                              // reuse after QKV GEMM
  unsigned short* ol    = ln1l;
  float* out1           = (float*)(ws + 80 * MB);            // 16MB fp32 residual
  unsigned short* ln2h  = (unsigned short*)(ws + 16 * MB);   // reuse (qkv dead)
  unsigned short* geluh = (unsigned short*)(ws + 24 * MB);   // reuse
  float* out2           = (float*)(ws + 32 * MB);            // 16MB fp32, reuse
  unsigned short* BtQKVh = (unsigned short*)(ws + 96 * MB);  // 1536x512
  unsigned short* BtQKVl = BtQKVh + 1536 * 512;
  unsigned short* BtOh   = BtQKVl + 1536 * 512;
  unsigned short* BtOl   = BtOh + 512 * 512;
  unsigned short* BtW1h  = BtOl + 512 * 512;
  unsigned short* BtW2h  = BtW1h + 512 * 512;
  float* qkvb            = (float*)(BtW2h + 512 * 512);

  dim3 tb32(32, 8);
  transpose_k<<<dim3(SS / 32, CC / 32, BB), tb32, 0, stream>>>(x, bufx, CC, SS);
  convert_weights<<<dim3(16, 2, 48), tb32, 0, stream>>>(
      Q_W, K_W, V_W, O_W, W1, W2, Q_b, K_b, V_b,
      BtQKVh, BtQKVl, BtOh, BtOl, BtW1h, BtW2h, qkvb);
  ln_bf16_k<<<BB * SS, 256, 0, stream>>>(bufx, ln1g, ln1b, ln1h, ln1l);
  // fused QKV projection (split, hi+lo out)
  gemm_mfma<1, 0, 2, 0><<<dim3(12, 64), 256, 0, stream>>>(
      ln1h, ln1l, BtQKVh, BtQKVl, qkvb, nullptr, qkvh, qkvl, nullptr, 3 * CC);
  attn_mfma<<<dim3(SS / 64, NHH, BB), 256, 0, stream>>>(qkvh, qkvl, oh, ol);
  // O projection (split) + residual(xs) -> out1 fp32
  gemm_mfma<1, 0, 0, 1><<<dim3(4, 64), 256, 0, stream>>>(
      oh, ol, BtOh, BtOl, O_b, bufx, nullptr, nullptr, out1, CC);
  ln_bf16_k<<<BB * SS, 256, 0, stream>>>(out1, ln2g, ln2b, ln2h, nullptr);
  // MLP (plain bf16): W1 + exact GELU -> bf16
  gemm_mfma<0, 1, 1, 0><<<dim3(4, 64), 256, 0, stream>>>(
      ln2h, nullptr, BtW1h, nullptr, b1, nullptr, geluh, nullptr, nullptr, CC);
  // W2 + residual(out1) -> fp32
  gemm_mfma<0, 0, 0, 1><<<dim3(4, 64), 256, 0, stream>>>(
      geluh, nullptr, BtW2h, nullptr, b2, out1, nullptr, nullptr, out2, CC);
  transpose_k<<<dim3(CC / 32, SS / 32, BB), tb32, 0, stream>>>(out2, out, SS, CC);
}

// Round 4
// 341.055 us; speedup vs baseline: 2.9690x; 1.1300x over previous
//
#include <hip/hip_runtime.h>
#include <math.h>

#define BB 8
#define CC 512
#define SS 1024
#define NHH 8
#define HDD 64
#define KD 512

typedef __attribute__((ext_vector_type(8))) short short8;
typedef __attribute__((ext_vector_type(4))) float f32x4;

__device__ __forceinline__ unsigned short f2bf(float x) {
  union { float f; unsigned int u; } c; c.f = x;
  unsigned int r = (c.u + 0x7FFFu + ((c.u >> 16) & 1u)) >> 16;
  return (unsigned short)r;
}
__device__ __forceinline__ float b2f(unsigned short h) {
  union { unsigned int u; float f; } c; c.u = ((unsigned int)h) << 16; return c.f;
}

#define GLD_LDS(gp, lp) __builtin_amdgcn_global_load_lds( \
    (const __attribute__((address_space(1))) void*)(gp),  \
    (__attribute__((address_space(3))) void*)(lp), 16, 0, 0)

// ---------- block-wide sum over 256 threads (4 waves) ----------
__device__ __forceinline__ float block_reduce_sum(float v) {
  __shared__ float sm[4];
  #pragma unroll
  for (int o = 32; o > 0; o >>= 1) v += __shfl_down(v, o, 64);
  if ((threadIdx.x & 63) == 0) sm[threadIdx.x >> 6] = v;
  __syncthreads();
  float r = (sm[0] + sm[1]) + (sm[2] + sm[3]);
  __syncthreads();
  return r;
}

// ---------- batched 2D transpose: in (B, d1, d2) -> out (B, d2, d1), fp32 ----
__global__ __launch_bounds__(256) void transpose_k(const float* __restrict__ in,
                                                   float* __restrict__ out,
                                                   int d1, int d2) {
  __shared__ float tile[32][33];
  int b = blockIdx.z;
  int j0 = blockIdx.x * 32;
  int i0 = blockIdx.y * 32;
  const float* inb = in + (size_t)b * d1 * d2;
  float* outb = out + (size_t)b * d1 * d2;
  int tx = threadIdx.x, ty = threadIdx.y;  // (32, 8)
  #pragma unroll
  for (int i = ty; i < 32; i += 8)
    tile[i][tx] = inb[(size_t)(i0 + i) * d2 + j0 + tx];
  __syncthreads();
  #pragma unroll
  for (int i = ty; i < 32; i += 8)
    outb[(size_t)(j0 + i) * d1 + i0 + tx] = tile[tx][i];
}

// ---------- LayerNorm (C=512) -> bf16 hi (+ optional lo plane) ---------------
__global__ __launch_bounds__(256) void ln_bf16_k(const float* __restrict__ in,
                                                 const float* __restrict__ g,
                                                 const float* __restrict__ be,
                                                 unsigned short* __restrict__ outh,
                                                 unsigned short* __restrict__ outl) {
  size_t row = blockIdx.x;
  const float* r = in + row * CC;
  int t = threadIdx.x;
  float v0 = r[t], v1 = r[t + 256];
  float s = block_reduce_sum(v0 + v1);
  float mu = s * (1.0f / CC);
  float d0 = v0 - mu, d1 = v1 - mu;
  float vs = block_reduce_sum(d0 * d0 + d1 * d1);
  float rstd = rsqrtf(vs * (1.0f / CC) + 1e-5f);
  float y0 = d0 * rstd * g[t] + be[t];
  float y1 = d1 * rstd * g[t + 256] + be[t + 256];
  unsigned short h0 = f2bf(y0), h1 = f2bf(y1);
  outh[row * CC + t]       = h0;
  outh[row * CC + t + 256] = h1;
  if (outl) {
    outl[row * CC + t]       = f2bf(y0 - b2f(h0));
    outl[row * CC + t + 256] = f2bf(y1 - b2f(h1));
  }
}

// ---------- weight convert: fp32 -> bf16 hi/lo B^T (N,K) ---------------------
// 48 panels: 0-7 QW, 8-15 KW (hi+lo), 16-23 VW (hi), 24-31 OW (hi+lo),
//            32-39 W1 (hi), 40-47 W2 (hi)
__global__ __launch_bounds__(256) void convert_weights(
    const float* __restrict__ QW, const float* __restrict__ KW,
    const float* __restrict__ VW, const float* __restrict__ OW,
    const float* __restrict__ W1, const float* __restrict__ W2,
    const float* __restrict__ Qb, const float* __restrict__ Kb,
    const float* __restrict__ Vb,
    unsigned short* __restrict__ BtQKh, unsigned short* __restrict__ BtQKl,
    unsigned short* __restrict__ BtVh,
    unsigned short* __restrict__ BtOh, unsigned short* __restrict__ BtOl,
    unsigned short* __restrict__ BtW1h, unsigned short* __restrict__ BtW2h,
    float* __restrict__ qkvb) {
  __shared__ float tile[32][33];
  const int p = blockIdx.z, wsel = p >> 3, sub = p & 7;
  const int k0 = blockIdx.x * 32, d0 = blockIdx.y * 32;
  const int tx = threadIdx.x, ty = threadIdx.y;
  const float* w; int rs; unsigned short *dh, *dl; int nbase;
  switch (wsel) {
    case 0:  w = QW + sub * 32768; rs = 64;  dh = BtQKh; dl = BtQKl;  nbase = sub * 64;        break;
    case 1:  w = KW + sub * 32768; rs = 64;  dh = BtQKh; dl = BtQKl;  nbase = 512 + sub * 64;  break;
    case 2:  w = VW + sub * 32768; rs = 64;  dh = BtVh;  dl = nullptr; nbase = sub * 64;       break;
    case 3:  w = OW + sub * 64;    rs = 512; dh = BtOh;  dl = BtOl;   nbase = sub * 64;        break;
    case 4:  w = W1 + sub * 64;    rs = 512; dh = BtW1h; dl = nullptr; nbase = sub * 64;       break;
    default: w = W2 + sub * 64;    rs = 512; dh = BtW2h; dl = nullptr; nbase = sub * 64;       break;
  }
  for (int i = ty; i < 32; i += 8)
    tile[i][tx] = w[(size_t)(k0 + i) * rs + d0 + tx];
  __syncthreads();
  for (int i = ty; i < 32; i += 8) {
    float f = tile[tx][i];
    unsigned short h = f2bf(f);
    size_t idx = (size_t)(nbase + d0 + i) * KD + k0 + tx;
    dh[idx] = h;
    if (dl) dl[idx] = f2bf(f - b2f(h));
  }
  if (p == 0 && blockIdx.x == 0 && blockIdx.y == 0) {
    int t = ty * 32 + tx;
    for (int i = t; i < 1536; i += 256)
      qkvb[i] = i < 512 ? Qb[i] : (i < 1024 ? Kb[i - 512] : Vb[i - 1024]);
  }
}

// ---------- MFMA GEMM: out[M, N] = A[M,512] @ Bt[N,512]^T + bias -------------
// SA/SB: A/B given as hi/lo bf16 planes (adds lh / hl MFMA terms).
// OUTMODE: 0 = fp32, 1 = bf16 hi, 2 = bf16 hi+lo
template<int SA, int SB, int GELU, int OUTMODE, int RESID>
__global__ __launch_bounds__(256) void gemm_mfma(
    const unsigned short* __restrict__ Ah, const unsigned short* __restrict__ Al,
    const unsigned short* __restrict__ Bh, const unsigned short* __restrict__ Bl,
    const float* __restrict__ bias, const float* __restrict__ resid,
    unsigned short* __restrict__ outh, unsigned short* __restrict__ outl,
    float* __restrict__ outf, int ldc) {
  __shared__ __align__(16) unsigned short As[(SA ? 2 : 1) * 128 * 32];
  __shared__ __align__(16) unsigned short Bs[(SB ? 2 : 1) * 128 * 32];
  const int tid = threadIdx.x;
  const int w = tid >> 6, l = tid & 63, quad = l >> 4, lm = l & 15;
  const int n0 = blockIdx.x * 128, m0 = blockIdx.y * 128;
  const int wm = (w >> 1) * 64, wn = (w & 1) * 64;
  const int srow = tid >> 2, sch = (tid & 3) * 8;
  const unsigned short* Agh = Ah + (size_t)(m0 + srow) * KD + sch;
  const unsigned short* Bgh = Bh + (size_t)(n0 + srow) * KD + sch;
  const unsigned short* Agl = SA ? Al + (size_t)(m0 + srow) * KD + sch : nullptr;
  const unsigned short* Bgl = SB ? Bl + (size_t)(n0 + srow) * KD + sch : nullptr;
  unsigned short* Aswh = As + w * 512;
  unsigned short* Bswh = Bs + w * 512;
  unsigned short* Aswl = As + 4096 + w * 512;
  unsigned short* Bswl = Bs + 4096 + w * 512;
  const f32x4 fzero = {0.f, 0.f, 0.f, 0.f};
  f32x4 acc[4][4];
  #pragma unroll
  for (int i = 0; i < 4; ++i)
    #pragma unroll
    for (int j = 0; j < 4; ++j) acc[i][j] = fzero;
  for (int k0 = 0; k0 < KD; k0 += 32) {
    __syncthreads();
    GLD_LDS(Agh + k0, Aswh);
    GLD_LDS(Agh + k0 + 64 * KD, Aswh + 2048);
    GLD_LDS(Bgh + k0, Bswh);
    GLD_LDS(Bgh + k0 + 64 * KD, Bswh + 2048);
    if constexpr (SA) {
      GLD_LDS(Agl + k0, Aswl);
      GLD_LDS(Agl + k0 + 64 * KD, Aswl + 2048);
    }
    if constexpr (SB) {
      GLD_LDS(Bgl + k0, Bswl);
      GLD_LDS(Bgl + k0 + 64 * KD, Bswl + 2048);
    }
    __syncthreads();
    short8 afh[4], bfh[4], afl[4], bfl[4];
    #pragma unroll
    for (int i = 0; i < 4; ++i)
      afh[i] = *(const short8*)(As + (wm + i * 16 + lm) * 32 + quad * 8);
    #pragma unroll
    for (int j = 0; j < 4; ++j)
      bfh[j] = *(const short8*)(Bs + (wn + j * 16 + lm) * 32 + quad * 8);
    if constexpr (SA) {
      #pragma unroll
      for (int i = 0; i < 4; ++i)
        afl[i] = *(const short8*)(As + 4096 + (wm + i * 16 + lm) * 32 + quad * 8);
    }
    if constexpr (SB) {
      #pragma unroll
      for (int j = 0; j < 4; ++j)
        bfl[j] = *(const short8*)(Bs + 4096 + (wn + j * 16 + lm) * 32 + quad * 8);
    }
    #pragma unroll
    for (int i = 0; i < 4; ++i)
      #pragma unroll
      for (int j = 0; j < 4; ++j) {
        f32x4 t = acc[i][j];
        t = __builtin_amdgcn_mfma_f32_16x16x32_bf16(afh[i], bfh[j], t, 0, 0, 0);
        if constexpr (SB)
          t = __builtin_amdgcn_mfma_f32_16x16x32_bf16(afh[i], bfl[j], t, 0, 0, 0);
        if constexpr (SA)
          t = __builtin_amdgcn_mfma_f32_16x16x32_bf16(afl[i], bfh[j], t, 0, 0, 0);
        acc[i][j] = t;
      }
  }
  #pragma unroll
  for (int i = 0; i < 4; ++i) {
    const int row = m0 + wm + i * 16 + quad * 4;
    #pragma unroll
    for (int j = 0; j < 4; ++j) {
      const int col = n0 + wn + j * 16 + lm;
      const float bv = bias[col];
      #pragma unroll
      for (int r = 0; r < 4; ++r) {
        float x = acc[i][j][r] + bv;
        if (GELU) x = 0.5f * x * (1.0f + erff(x * 0.70710678118654752f));
        if (RESID) x += resid[(size_t)(row + r) * CC + col];
        const size_t oi = (size_t)(row + r) * ldc + col;
        if (OUTMODE == 0) {
          outf[oi] = x;
        } else if (OUTMODE == 1) {
          outh[oi] = f2bf(x);
        } else {
          unsigned short h = f2bf(x);
          outh[oi] = h;
          outl[oi] = f2bf(x - b2f(h));
        }
      }
    }
  }
}

// ---------- flash attention: 128 q-rows/block, split QK^T, plain PV ----------
// QK hi/lo: (B, S, 1024) bf16 [Q | K]; V hi: (B, S, 512); O hi: (B, S, 512)
__global__ __launch_bounds__(256) void attn_mfma(
    const unsigned short* __restrict__ QKh, const unsigned short* __restrict__ QKl,
    const unsigned short* __restrict__ Vh, unsigned short* __restrict__ Oh) {
  __shared__ __align__(16) unsigned short Ksh[64 * 72], Ksl[64 * 72];
  __shared__ __align__(16) unsigned short Vth[64 * 72];
  __shared__ __align__(16) unsigned short Psh[4 * 32 * 72];  // per-wave 32 rows
  const int q0 = blockIdx.x * 128, h = blockIdx.y, b = blockIdx.z;
  const int tid = threadIdx.x, w = tid >> 6, l = tid & 63, quad = l >> 4, lm = l & 15;
  const int LDQ = 2 * CC;
  const size_t qkbase = (size_t)b * SS * LDQ;
  const size_t vbase  = (size_t)b * SS * CC;
  const int srow = tid >> 2, sch = (tid & 3) * 8;
  // Q fragments in registers (A-layout: m=lm, k=st*32+quad*8), 2 row-groups
  short8 qh[2][2], ql[2][2];
  #pragma unroll
  for (int g = 0; g < 2; ++g) {
    const size_t qo = qkbase + (size_t)(q0 + g * 64 + w * 16 + lm) * LDQ + h * 64 + quad * 8;
    qh[g][0] = *(const short8*)(QKh + qo);
    qh[g][1] = *(const short8*)(QKh + qo + 32);
    ql[g][0] = *(const short8*)(QKl + qo);
    ql[g][1] = *(const short8*)(QKl + qo + 32);
  }
  const f32x4 fzero = {0.f, 0.f, 0.f, 0.f};
  float mrow[2][4], lrow[2][4];
  f32x4 oacc[2][4];
  #pragma unroll
  for (int g = 0; g < 2; ++g) {
    #pragma unroll
    for (int r = 0; r < 4; ++r) { mrow[g][r] = -1e30f; lrow[g][r] = 0.f; }
    #pragma unroll
    for (int j = 0; j < 4; ++j) oacc[g][j] = fzero;
  }
  const float scale = 0.044194173824159216f;  // 1/sqrt(512)
  unsigned short* Pw = Psh + w * (32 * 72);
  for (int kt = 0; kt < SS; kt += 64) {
    __syncthreads();  // previous tile fully consumed
    {
      const size_t ko = qkbase + (size_t)(kt + srow) * LDQ + CC + h * 64 + sch;
      *(short8*)(Ksh + srow * 72 + sch)      = *(const short8*)(QKh + ko);
      *(short8*)(Ksh + srow * 72 + sch + 32) = *(const short8*)(QKh + ko + 32);
      *(short8*)(Ksl + srow * 72 + sch)      = *(const short8*)(QKl + ko);
      *(short8*)(Ksl + srow * 72 + sch + 32) = *(const short8*)(QKl + ko + 32);
      #pragma unroll
      for (int pass = 0; pass < 2; ++pass) {
        const int c = w + pass * 4;
        const size_t vo = vbase + (size_t)(kt + l) * CC + h * 64 + c * 8;
        short8 vh8 = *(const short8*)(Vh + vo);
        #pragma unroll
        for (int u = 0; u < 8; ++u) Vth[(c * 8 + u) * 72 + l] = (unsigned short)vh8[u];
      }
    }
    __syncthreads();
    #pragma unroll
    for (int g = 0; g < 2; ++g) {
      // scores (bf16x3): group g's 16 q-rows vs 64 keys
      f32x4 sc[4];
      #pragma unroll
      for (int j = 0; j < 4; ++j) sc[j] = fzero;
      #pragma unroll
      for (int st = 0; st < 2; ++st) {
        #pragma unroll
        for (int j = 0; j < 4; ++j) {
          short8 kh = *(const short8*)(Ksh + (j * 16 + lm) * 72 + st * 32 + quad * 8);
          short8 kl = *(const short8*)(Ksl + (j * 16 + lm) * 72 + st * 32 + quad * 8);
          f32x4 t = sc[j];
          t = __builtin_amdgcn_mfma_f32_16x16x32_bf16(qh[g][st], kh, t, 0, 0, 0);
          t = __builtin_amdgcn_mfma_f32_16x16x32_bf16(qh[g][st], kl, t, 0, 0, 0);
          t = __builtin_amdgcn_mfma_f32_16x16x32_bf16(ql[g][st], kh, t, 0, 0, 0);
          sc[j] = t;
        }
      }
      #pragma unroll
      for (int j = 0; j < 4; ++j) sc[j] *= scale;
      // online softmax (C-layout: col=lm, row=quad*4+r)
      #pragma unroll
      for (int r = 0; r < 4; ++r) {
        float mt = fmaxf(fmaxf(sc[0][r], sc[1][r]), fmaxf(sc[2][r], sc[3][r]));
        #pragma unroll
        for (int mask = 1; mask < 16; mask <<= 1) mt = fmaxf(mt, __shfl_xor(mt, mask, 64));
        const float mn = fmaxf(mrow[g][r], mt);
        const float alpha = __expf(mrow[g][r] - mn);
        mrow[g][r] = mn;
        float ls = 0.f;
        #pragma unroll
        for (int j = 0; j < 4; ++j) {
          const float p = __expf(sc[j][r] - mn);
          sc[j][r] = p;
          ls += p;
        }
        #pragma unroll
        for (int mask = 1; mask < 16; mask <<= 1) ls += __shfl_xor(ls, mask, 64);
        lrow[g][r] = lrow[g][r] * alpha + ls;
        #pragma unroll
        for (int j = 0; j < 4; ++j) oacc[g][j][r] *= alpha;
      }
      // P -> per-wave LDS (A-layout), rows g*16 + quad*4+r
      #pragma unroll
      for (int r = 0; r < 4; ++r)
        #pragma unroll
        for (int j = 0; j < 4; ++j)
          Pw[(g * 16 + quad * 4 + r) * 72 + j * 16 + lm] = f2bf(sc[j][r]);
    }
    __syncthreads();  // P visible (also keeps waves in step)
    #pragma unroll
    for (int g = 0; g < 2; ++g)
      #pragma unroll
      for (int st = 0; st < 2; ++st) {
        short8 ap = *(const short8*)(Pw + (g * 16 + lm) * 72 + st * 32 + quad * 8);
        #pragma unroll
        for (int j = 0; j < 4; ++j) {
          short8 vv = *(const short8*)(Vth + (j * 16 + lm) * 72 + st * 32 + quad * 8);
          oacc[g][j] = __builtin_amdgcn_mfma_f32_16x16x32_bf16(ap, vv, oacc[g][j], 0, 0, 0);
        }
      }
  }
  #pragma unroll
  for (int g = 0; g < 2; ++g) {
    float inv[4];
    #pragma unroll
    for (int r = 0; r < 4; ++r) inv[r] = 1.f / lrow[g][r];
    const size_t obase =
        vbase + (size_t)(q0 + g * 64 + w * 16 + quad * 4) * CC + h * 64 + lm;
    #pragma unroll
    for (int j = 0; j < 4; ++j)
      #pragma unroll
      for (int r = 0; r < 4; ++r)
        Oh[obase + (size_t)r * CC + j * 16] = f2bf(oacc[g][j][r] * inv[r]);
  }
}

extern "C" void kernel_launch(void* const* d_in, const int* in_sizes, int n_in,
                              void* d_out, int out_size, void* d_ws, size_t ws_size,
                              hipStream_t stream) {
  const float* x    = (const float*)d_in[0];
  const float* K_W  = (const float*)d_in[2];
  const float* K_b  = (const float*)d_in[3];
  const float* Q_W  = (const float*)d_in[4];
  const float* Q_b  = (const float*)d_in[5];
  const float* V_W  = (const float*)d_in[6];
  const float* V_b  = (const float*)d_in[7];
  const float* O_W  = (const float*)d_in[8];
  const float* O_b  = (const float*)d_in[9];
  const float* ln1g = (const float*)d_in[10];
  const float* ln1b = (const float*)d_in[11];
  const float* ln2g = (const float*)d_in[12];
  const float* ln2b = (const float*)d_in[13];
  const float* W1   = (const float*)d_in[14];
  const float* b1   = (const float*)d_in[15];
  const float* W2   = (const float*)d_in[16];
  const float* b2   = (const float*)d_in[17];
  float* out = (float*)d_out;

  unsigned char* ws = (unsigned char*)d_ws;
  const size_t MB = 1u << 20;
  float* bufx           = (float*)(ws);                      // xs fp32, 16MB
  unsigned short* qkh   = (unsigned short*)(ws + 16 * MB);   // (B,S,1024) 16MB
  unsigned short* qkl   = (unsigned short*)(ws + 32 * MB);   // 16MB
  unsigned short* vh    = (unsigned short*)(ws + 48 * MB);   // (B,S,512) 8MB
  unsigned short* ln1h  = (unsigned short*)(ws + 56 * MB);   // 8MB
  unsigned short* ln1l  = (unsigned short*)(ws + 64 * MB);   // 8MB
  unsigned short* oh    = ln1h;                              // reuse after QKV GEMMs
  float* out1           = (float*)(ws + 72 * MB);            // 16MB fp32 residual
  unsigned short* ln2h  = (unsigned short*)(ws + 16 * MB);   // reuse qkh (dead post-attn)
  unsigned short* geluh = (unsigned short*)(ws + 24 * MB);   // reuse qkh 2nd half
  float* out2           = (float*)(ws + 32 * MB);            // reuse qkl, 16MB
  unsigned short* BtQKh = (unsigned short*)(ws + 88 * MB);   // 1024x512
  unsigned short* BtQKl = BtQKh + 1024 * 512;
  unsigned short* BtVh  = BtQKl + 1024 * 512;
  unsigned short* BtOh  = BtVh + 512 * 512;
  unsigned short* BtOl  = BtOh + 512 * 512;
  unsigned short* BtW1h = BtOl + 512 * 512;
  unsigned short* BtW2h = BtW1h + 512 * 512;
  float* qkvb           = (float*)(BtW2h + 512 * 512);

  dim3 tb32(32, 8);
  transpose_k<<<dim3(SS / 32, CC / 32, BB), tb32, 0, stream>>>(x, bufx, CC, SS);
  convert_weights<<<dim3(16, 2, 48), tb32, 0, stream>>>(
      Q_W, K_W, V_W, O_W, W1, W2, Q_b, K_b, V_b,
      BtQKh, BtQKl, BtVh, BtOh, BtOl, BtW1h, BtW2h, qkvb);
  ln_bf16_k<<<BB * SS, 256, 0, stream>>>(bufx, ln1g, ln1b, ln1h, ln1l);
  // QK projection (split A,B; hi+lo out), N=1024
  gemm_mfma<1, 1, 0, 2, 0><<<dim3(8, 64), 256, 0, stream>>>(
      ln1h, ln1l, BtQKh, BtQKl, qkvb, nullptr, qkh, qkl, nullptr, 2 * CC);
  // V projection (plain), N=512
  gemm_mfma<0, 0, 0, 1, 0><<<dim3(4, 64), 256, 0, stream>>>(
      ln1h, nullptr, BtVh, nullptr, qkvb + 1024, nullptr, vh, nullptr, nullptr, CC);
  attn_mfma<<<dim3(SS / 128, NHH, BB), 256, 0, stream>>>(qkh, qkl, vh, oh);
  // O projection (B split) + residual(xs) -> out1 fp32
  gemm_mfma<0, 1, 0, 0, 1><<<dim3(4, 64), 256, 0, stream>>>(
      oh, nullptr, BtOh, BtOl, O_b, bufx, nullptr, nullptr, out1, CC);
  ln_bf16_k<<<BB * SS, 256, 0, stream>>>(out1, ln2g, ln2b, ln2h, nullptr);
  // MLP: W1 + exact GELU -> bf16
  gemm_mfma<0, 0, 1, 1, 0><<<dim3(4, 64), 256, 0, stream>>>(
      ln2h, nullptr, BtW1h, nullptr, b1, nullptr, geluh, nullptr, nullptr, CC);
  // W2 + residual(out1) -> fp32
  gemm_mfma<0, 0, 0, 0, 1><<<dim3(4, 64), 256, 0, stream>>>(
      geluh, nullptr, BtW2h, nullptr, b2, out1, nullptr, nullptr, out2, CC);
  transpose_k<<<dim3(CC / 32, SS / 32, BB), tb32, 0, stream>>>(out2, out, SS, CC);
}

// Round 5
// 321.885 us; speedup vs baseline: 3.1458x; 1.0596x over previous
//
#include <hip/hip_runtime.h>
#include <math.h>

#define BB 8
#define CC 512
#define SS 1024
#define NHH 8
#define HDD 64
#define KD 512

typedef __attribute__((ext_vector_type(8))) short short8;
typedef __attribute__((ext_vector_type(4))) float f32x4;

__device__ __forceinline__ unsigned short f2bf(float x) {
  union { float f; unsigned int u; } c; c.f = x;
  unsigned int r = (c.u + 0x7FFFu + ((c.u >> 16) & 1u)) >> 16;
  return (unsigned short)r;
}
__device__ __forceinline__ float b2f(unsigned short h) {
  union { unsigned int u; float f; } c; c.u = ((unsigned int)h) << 16; return c.f;
}

#define GLD_LDS(gp, lp) __builtin_amdgcn_global_load_lds( \
    (const __attribute__((address_space(1))) void*)(gp),  \
    (__attribute__((address_space(3))) void*)(lp), 16, 0, 0)

// ---------- block-wide sum over 256 threads (4 waves) ----------
__device__ __forceinline__ float block_reduce_sum(float v) {
  __shared__ float sm[4];
  #pragma unroll
  for (int o = 32; o > 0; o >>= 1) v += __shfl_down(v, o, 64);
  if ((threadIdx.x & 63) == 0) sm[threadIdx.x >> 6] = v;
  __syncthreads();
  float r = (sm[0] + sm[1]) + (sm[2] + sm[3]);
  __syncthreads();
  return r;
}

// ---------- batched 2D transpose: in (B, d1, d2) -> out (B, d2, d1), fp32 ----
__global__ __launch_bounds__(256) void transpose_k(const float* __restrict__ in,
                                                   float* __restrict__ out,
                                                   int d1, int d2) {
  __shared__ float tile[32][33];
  int b = blockIdx.z;
  int j0 = blockIdx.x * 32;
  int i0 = blockIdx.y * 32;
  const float* inb = in + (size_t)b * d1 * d2;
  float* outb = out + (size_t)b * d1 * d2;
  int tx = threadIdx.x, ty = threadIdx.y;  // (32, 8)
  #pragma unroll
  for (int i = ty; i < 32; i += 8)
    tile[i][tx] = inb[(size_t)(i0 + i) * d2 + j0 + tx];
  __syncthreads();
  #pragma unroll
  for (int i = ty; i < 32; i += 8)
    outb[(size_t)(j0 + i) * d1 + i0 + tx] = tile[tx][i];
}

// ---------- LayerNorm (C=512) -> bf16 hi (+ optional lo plane) ---------------
__global__ __launch_bounds__(256) void ln_bf16_k(const float* __restrict__ in,
                                                 const float* __restrict__ g,
                                                 const float* __restrict__ be,
                                                 unsigned short* __restrict__ outh,
                                                 unsigned short* __restrict__ outl) {
  size_t row = blockIdx.x;
  const float* r = in + row * CC;
  int t = threadIdx.x;
  float v0 = r[t], v1 = r[t + 256];
  float s = block_reduce_sum(v0 + v1);
  float mu = s * (1.0f / CC);
  float d0 = v0 - mu, d1 = v1 - mu;
  float vs = block_reduce_sum(d0 * d0 + d1 * d1);
  float rstd = rsqrtf(vs * (1.0f / CC) + 1e-5f);
  float y0 = d0 * rstd * g[t] + be[t];
  float y1 = d1 * rstd * g[t + 256] + be[t + 256];
  unsigned short h0 = f2bf(y0), h1 = f2bf(y1);
  outh[row * CC + t]       = h0;
  outh[row * CC + t + 256] = h1;
  if (outl) {
    outl[row * CC + t]       = f2bf(y0 - b2f(h0));
    outl[row * CC + t + 256] = f2bf(y1 - b2f(h1));
  }
}

// ---------- weight convert: fp32 -> bf16 hi/lo B^T (N,K) ---------------------
// 48 panels: 0-7 QW, 8-15 KW (hi+lo), 16-23 VW (hi), 24-31 OW (hi+lo),
//            32-39 W1 (hi), 40-47 W2 (hi)
__global__ __launch_bounds__(256) void convert_weights(
    const float* __restrict__ QW, const float* __restrict__ KW,
    const float* __restrict__ VW, const float* __restrict__ OW,
    const float* __restrict__ W1, const float* __restrict__ W2,
    const float* __restrict__ Qb, const float* __restrict__ Kb,
    const float* __restrict__ Vb,
    unsigned short* __restrict__ BtQKh, unsigned short* __restrict__ BtQKl,
    unsigned short* __restrict__ BtVh,
    unsigned short* __restrict__ BtOh, unsigned short* __restrict__ BtOl,
    unsigned short* __restrict__ BtW1h, unsigned short* __restrict__ BtW2h,
    float* __restrict__ qkvb) {
  __shared__ float tile[32][33];
  const int p = blockIdx.z, wsel = p >> 3, sub = p & 7;
  const int k0 = blockIdx.x * 32, d0 = blockIdx.y * 32;
  const int tx = threadIdx.x, ty = threadIdx.y;
  const float* w; int rs; unsigned short *dh, *dl; int nbase;
  switch (wsel) {
    case 0:  w = QW + sub * 32768; rs = 64;  dh = BtQKh; dl = BtQKl;  nbase = sub * 64;        break;
    case 1:  w = KW + sub * 32768; rs = 64;  dh = BtQKh; dl = BtQKl;  nbase = 512 + sub * 64;  break;
    case 2:  w = VW + sub * 32768; rs = 64;  dh = BtVh;  dl = nullptr; nbase = sub * 64;       break;
    case 3:  w = OW + sub * 64;    rs = 512; dh = BtOh;  dl = BtOl;   nbase = sub * 64;        break;
    case 4:  w = W1 + sub * 64;    rs = 512; dh = BtW1h; dl = nullptr; nbase = sub * 64;       break;
    default: w = W2 + sub * 64;    rs = 512; dh = BtW2h; dl = nullptr; nbase = sub * 64;       break;
  }
  for (int i = ty; i < 32; i += 8)
    tile[i][tx] = w[(size_t)(k0 + i) * rs + d0 + tx];
  __syncthreads();
  for (int i = ty; i < 32; i += 8) {
    float f = tile[tx][i];
    unsigned short h = f2bf(f);
    size_t idx = (size_t)(nbase + d0 + i) * KD + k0 + tx;
    dh[idx] = h;
    if (dl) dl[idx] = f2bf(f - b2f(h));
  }
  if (p == 0 && blockIdx.x == 0 && blockIdx.y == 0) {
    int t = ty * 32 + tx;
    for (int i = t; i < 1536; i += 256)
      qkvb[i] = i < 512 ? Qb[i] : (i < 1024 ? Kb[i - 512] : Vb[i - 1024]);
  }
}

// ---------- fused QKV projection GEMM, 128x128 tiles -------------------------
// Bth = [QK hi (1024) | V hi (512)] x 512; QK tiles: split A&B, hi+lo out;
// V tiles: plain (hh only, identical numerics to a plain GEMM).
__global__ __launch_bounds__(256) void gemm_qkv(
    const unsigned short* __restrict__ Ah, const unsigned short* __restrict__ Al,
    const unsigned short* __restrict__ Bth, const unsigned short* __restrict__ Btl,
    const float* __restrict__ bias,
    unsigned short* __restrict__ qkh, unsigned short* __restrict__ qkl,
    unsigned short* __restrict__ vh) {
  __shared__ __align__(16) unsigned short As[2 * 128 * 32];
  __shared__ __align__(16) unsigned short Bs[2 * 128 * 32];
  const int tid = threadIdx.x;
  const int w = tid >> 6, l = tid & 63, quad = l >> 4, lm = l & 15;
  const int n0 = blockIdx.x * 128, m0 = blockIdx.y * 128;
  const bool splitB = n0 < 1024;
  const int wm = (w >> 1) * 64, wn = (w & 1) * 64;
  const int srow = tid >> 2, sch = (tid & 3) * 8;
  const unsigned short* Agh = Ah + (size_t)(m0 + srow) * KD + sch;
  const unsigned short* Agl = Al + (size_t)(m0 + srow) * KD + sch;
  const unsigned short* Bgh = Bth + (size_t)(n0 + srow) * KD + sch;
  const unsigned short* Bgl = Btl + (size_t)(n0 + srow) * KD + sch;
  unsigned short* Aswh = As + w * 512;
  unsigned short* Aswl = As + 4096 + w * 512;
  unsigned short* Bswh = Bs + w * 512;
  unsigned short* Bswl = Bs + 4096 + w * 512;
  const f32x4 fzero = {0.f, 0.f, 0.f, 0.f};
  f32x4 acc[4][4];
  #pragma unroll
  for (int i = 0; i < 4; ++i)
    #pragma unroll
    for (int j = 0; j < 4; ++j) acc[i][j] = fzero;
  for (int k0 = 0; k0 < KD; k0 += 32) {
    __syncthreads();
    GLD_LDS(Agh + k0, Aswh);
    GLD_LDS(Agh + k0 + 64 * KD, Aswh + 2048);
    GLD_LDS(Agl + k0, Aswl);
    GLD_LDS(Agl + k0 + 64 * KD, Aswl + 2048);
    GLD_LDS(Bgh + k0, Bswh);
    GLD_LDS(Bgh + k0 + 64 * KD, Bswh + 2048);
    if (splitB) {
      GLD_LDS(Bgl + k0, Bswl);
      GLD_LDS(Bgl + k0 + 64 * KD, Bswl + 2048);
    }
    __syncthreads();
    short8 afh[4], afl[4], bfh[4], bfl[4];
    #pragma unroll
    for (int i = 0; i < 4; ++i) {
      afh[i] = *(const short8*)(As + (wm + i * 16 + lm) * 32 + quad * 8);
      afl[i] = *(const short8*)(As + 4096 + (wm + i * 16 + lm) * 32 + quad * 8);
    }
    #pragma unroll
    for (int j = 0; j < 4; ++j)
      bfh[j] = *(const short8*)(Bs + (wn + j * 16 + lm) * 32 + quad * 8);
    if (splitB) {
      #pragma unroll
      for (int j = 0; j < 4; ++j)
        bfl[j] = *(const short8*)(Bs + 4096 + (wn + j * 16 + lm) * 32 + quad * 8);
      #pragma unroll
      for (int i = 0; i < 4; ++i)
        #pragma unroll
        for (int j = 0; j < 4; ++j) {
          f32x4 t = acc[i][j];
          t = __builtin_amdgcn_mfma_f32_16x16x32_bf16(afh[i], bfh[j], t, 0, 0, 0);
          t = __builtin_amdgcn_mfma_f32_16x16x32_bf16(afh[i], bfl[j], t, 0, 0, 0);
          t = __builtin_amdgcn_mfma_f32_16x16x32_bf16(afl[i], bfh[j], t, 0, 0, 0);
          acc[i][j] = t;
        }
    } else {
      #pragma unroll
      for (int i = 0; i < 4; ++i)
        #pragma unroll
        for (int j = 0; j < 4; ++j)
          acc[i][j] = __builtin_amdgcn_mfma_f32_16x16x32_bf16(afh[i], bfh[j], acc[i][j], 0, 0, 0);
    }
  }
  #pragma unroll
  for (int i = 0; i < 4; ++i) {
    const int row = m0 + wm + i * 16 + quad * 4;
    #pragma unroll
    for (int j = 0; j < 4; ++j) {
      const int ncol = n0 + wn + j * 16 + lm;
      const float bv = bias[ncol];
      #pragma unroll
      for (int r = 0; r < 4; ++r) {
        float x = acc[i][j][r] + bv;
        if (splitB) {
          const size_t oi = (size_t)(row + r) * 1024 + ncol;
          unsigned short h = f2bf(x);
          qkh[oi] = h;
          qkl[oi] = f2bf(x - b2f(h));
        } else {
          vh[(size_t)(row + r) * 512 + (ncol - 1024)] = f2bf(x);
        }
      }
    }
  }
}

// ---------- 64x64-tile GEMM: out[M, N] = A[M,512] @ Bt[N,512]^T + bias -------
// SB: B hi/lo split (hh then hl, same order as before). OUTMODE: 0 fp32, 1 bf16 hi.
template<int SB, int GELU, int OUTMODE, int RESID>
__global__ __launch_bounds__(256) void gemm64(
    const unsigned short* __restrict__ Ah,
    const unsigned short* __restrict__ Bh, const unsigned short* __restrict__ Bl,
    const float* __restrict__ bias, const float* __restrict__ resid,
    unsigned short* __restrict__ outh, float* __restrict__ outf, int ldc) {
  __shared__ __align__(16) unsigned short As[64 * 32];
  __shared__ __align__(16) unsigned short Bs[(SB ? 2 : 1) * 64 * 32];
  const int tid = threadIdx.x;
  const int w = tid >> 6, l = tid & 63, quad = l >> 4, lm = l & 15;
  const int n0 = blockIdx.x * 64, m0 = blockIdx.y * 64;
  const int wm = (w >> 1) * 32, wn = (w & 1) * 32;
  const int srow = tid >> 2, sch = (tid & 3) * 8;
  const unsigned short* Ag = Ah + (size_t)(m0 + srow) * KD + sch;
  const unsigned short* Bg = Bh + (size_t)(n0 + srow) * KD + sch;
  const unsigned short* Bgl = SB ? Bl + (size_t)(n0 + srow) * KD + sch : nullptr;
  unsigned short* Asw = As + w * 512;
  unsigned short* Bsw = Bs + w * 512;
  unsigned short* Bswl = Bs + 2048 + w * 512;
  const f32x4 fzero = {0.f, 0.f, 0.f, 0.f};
  f32x4 acc[2][2];
  #pragma unroll
  for (int i = 0; i < 2; ++i)
    #pragma unroll
    for (int j = 0; j < 2; ++j) acc[i][j] = fzero;
  for (int k0 = 0; k0 < KD; k0 += 32) {
    __syncthreads();
    GLD_LDS(Ag + k0, Asw);
    GLD_LDS(Bg + k0, Bsw);
    if constexpr (SB) GLD_LDS(Bgl + k0, Bswl);
    __syncthreads();
    short8 af[2], bfh[2], bfl[2];
    #pragma unroll
    for (int i = 0; i < 2; ++i)
      af[i] = *(const short8*)(As + (wm + i * 16 + lm) * 32 + quad * 8);
    #pragma unroll
    for (int j = 0; j < 2; ++j)
      bfh[j] = *(const short8*)(Bs + (wn + j * 16 + lm) * 32 + quad * 8);
    if constexpr (SB) {
      #pragma unroll
      for (int j = 0; j < 2; ++j)
        bfl[j] = *(const short8*)(Bs + 2048 + (wn + j * 16 + lm) * 32 + quad * 8);
    }
    #pragma unroll
    for (int i = 0; i < 2; ++i)
      #pragma unroll
      for (int j = 0; j < 2; ++j) {
        f32x4 t = acc[i][j];
        t = __builtin_amdgcn_mfma_f32_16x16x32_bf16(af[i], bfh[j], t, 0, 0, 0);
        if constexpr (SB)
          t = __builtin_amdgcn_mfma_f32_16x16x32_bf16(af[i], bfl[j], t, 0, 0, 0);
        acc[i][j] = t;
      }
  }
  #pragma unroll
  for (int i = 0; i < 2; ++i) {
    const int row = m0 + wm + i * 16 + quad * 4;
    #pragma unroll
    for (int j = 0; j < 2; ++j) {
      const int col = n0 + wn + j * 16 + lm;
      const float bv = bias[col];
      #pragma unroll
      for (int r = 0; r < 4; ++r) {
        float x = acc[i][j][r] + bv;
        if (GELU) x = 0.5f * x * (1.0f + erff(x * 0.70710678118654752f));
        if (RESID) x += resid[(size_t)(row + r) * CC + col];
        const size_t oi = (size_t)(row + r) * ldc + col;
        if (OUTMODE == 0) outf[oi] = x;
        else outh[oi] = f2bf(x);
      }
    }
  }
}

// ---------- flash attention: 64 q-rows/block, split QK^T, plain PV -----------
// QK hi/lo: (B, S, 1024) bf16 [Q | K]; V hi: (B, S, 512); O hi: (B, S, 512)
__global__ __launch_bounds__(256) void attn_mfma(
    const unsigned short* __restrict__ QKh, const unsigned short* __restrict__ QKl,
    const unsigned short* __restrict__ Vh, unsigned short* __restrict__ Oh) {
  __shared__ __align__(16) unsigned short Ksh[64 * 72], Ksl[64 * 72];
  __shared__ __align__(16) unsigned short Vth[64 * 72];
  __shared__ __align__(16) unsigned short Ps[4 * 16 * 88];  // per-wave 16 rows, stride 88
  const int q0 = blockIdx.x * 64, h = blockIdx.y, b = blockIdx.z;
  const int tid = threadIdx.x, w = tid >> 6, l = tid & 63, quad = l >> 4, lm = l & 15;
  const int LDQ = 2 * CC;
  const size_t qkbase = (size_t)b * SS * LDQ;
  const size_t vbase  = (size_t)b * SS * CC;
  const int srow = tid >> 2, sch = (tid & 3) * 8;
  // Q fragments in registers (A-layout: m=lm, k=st*32+quad*8)
  short8 qh[2], ql[2];
  {
    const size_t qo = qkbase + (size_t)(q0 + w * 16 + lm) * LDQ + h * 64 + quad * 8;
    qh[0] = *(const short8*)(QKh + qo);
    qh[1] = *(const short8*)(QKh + qo + 32);
    ql[0] = *(const short8*)(QKl + qo);
    ql[1] = *(const short8*)(QKl + qo + 32);
  }
  const f32x4 fzero = {0.f, 0.f, 0.f, 0.f};
  float mrow[4], lrow[4];
  f32x4 oacc[4];
  #pragma unroll
  for (int r = 0; r < 4; ++r) { mrow[r] = -1e30f; lrow[r] = 0.f; }
  #pragma unroll
  for (int j = 0; j < 4; ++j) oacc[j] = fzero;
  const float scale = 0.044194173824159216f;  // 1/sqrt(512)
  unsigned short* Pw = Ps + w * (16 * 88);
  for (int kt = 0; kt < SS; kt += 64) {
    __syncthreads();  // previous tile fully consumed
    {
      const size_t ko = qkbase + (size_t)(kt + srow) * LDQ + CC + h * 64 + sch;
      *(short8*)(Ksh + srow * 72 + sch)      = *(const short8*)(QKh + ko);
      *(short8*)(Ksh + srow * 72 + sch + 32) = *(const short8*)(QKh + ko + 32);
      *(short8*)(Ksl + srow * 72 + sch)      = *(const short8*)(QKl + ko);
      *(short8*)(Ksl + srow * 72 + sch + 32) = *(const short8*)(QKl + ko + 32);
      #pragma unroll
      for (int pass = 0; pass < 2; ++pass) {
        const int c = w + pass * 4;
        const size_t vo = vbase + (size_t)(kt + l) * CC + h * 64 + c * 8;
        short8 vh8 = *(const short8*)(Vh + vo);
        #pragma unroll
        for (int u = 0; u < 8; ++u) Vth[(c * 8 + u) * 72 + l] = (unsigned short)vh8[u];
      }
    }
    __syncthreads();  // tiles visible
    // scores (bf16x3): wave w's 16 q-rows vs 64 keys
    f32x4 sc[4];
    #pragma unroll
    for (int j = 0; j < 4; ++j) sc[j] = fzero;
    #pragma unroll
    for (int st = 0; st < 2; ++st) {
      #pragma unroll
      for (int j = 0; j < 4; ++j) {
        short8 kh = *(const short8*)(Ksh + (j * 16 + lm) * 72 + st * 32 + quad * 8);
        short8 kl = *(const short8*)(Ksl + (j * 16 + lm) * 72 + st * 32 + quad * 8);
        f32x4 t = sc[j];
        t = __builtin_amdgcn_mfma_f32_16x16x32_bf16(qh[st], kh, t, 0, 0, 0);
        t = __builtin_amdgcn_mfma_f32_16x16x32_bf16(qh[st], kl, t, 0, 0, 0);
        t = __builtin_amdgcn_mfma_f32_16x16x32_bf16(ql[st], kh, t, 0, 0, 0);
        sc[j] = t;
      }
    }
    #pragma unroll
    for (int j = 0; j < 4; ++j) sc[j] *= scale;
    // online softmax (C-layout: col=lm, row=quad*4+r)
    #pragma unroll
    for (int r = 0; r < 4; ++r) {
      float mt = fmaxf(fmaxf(sc[0][r], sc[1][r]), fmaxf(sc[2][r], sc[3][r]));
      #pragma unroll
      for (int mask = 1; mask < 16; mask <<= 1) mt = fmaxf(mt, __shfl_xor(mt, mask, 64));
      const float mn = fmaxf(mrow[r], mt);
      const float alpha = __expf(mrow[r] - mn);
      mrow[r] = mn;
      float ls = 0.f;
      #pragma unroll
      for (int j = 0; j < 4; ++j) {
        const float p = __expf(sc[j][r] - mn);
        sc[j][r] = p;
        ls += p;
      }
      #pragma unroll
      for (int mask = 1; mask < 16; mask <<= 1) ls += __shfl_xor(ls, mask, 64);
      lrow[r] = lrow[r] * alpha + ls;
      #pragma unroll
      for (int j = 0; j < 4; ++j) oacc[j][r] *= alpha;
    }
    // P -> per-wave LDS (A-layout); same-wave producer/consumer, no barrier needed
    #pragma unroll
    for (int r = 0; r < 4; ++r)
      #pragma unroll
      for (int j = 0; j < 4; ++j)
        Pw[(quad * 4 + r) * 88 + j * 16 + lm] = f2bf(sc[j][r]);
    #pragma unroll
    for (int st = 0; st < 2; ++st) {
      short8 ap = *(const short8*)(Pw + lm * 88 + st * 32 + quad * 8);
      #pragma unroll
      for (int j = 0; j < 4; ++j) {
        short8 vv = *(const short8*)(Vth + (j * 16 + lm) * 72 + st * 32 + quad * 8);
        oacc[j] = __builtin_amdgcn_mfma_f32_16x16x32_bf16(ap, vv, oacc[j], 0, 0, 0);
      }
    }
  }
  float inv[4];
  #pragma unroll
  for (int r = 0; r < 4; ++r) inv[r] = 1.f / lrow[r];
  const size_t obase = vbase + (size_t)(q0 + w * 16 + quad * 4) * CC + h * 64 + lm;
  #pragma unroll
  for (int j = 0; j < 4; ++j)
    #pragma unroll
    for (int r = 0; r < 4; ++r)
      Oh[obase + (size_t)r * CC + j * 16] = f2bf(oacc[j][r] * inv[r]);
}

extern "C" void kernel_launch(void* const* d_in, const int* in_sizes, int n_in,
                              void* d_out, int out_size, void* d_ws, size_t ws_size,
                              hipStream_t stream) {
  const float* x    = (const float*)d_in[0];
  const float* K_W  = (const float*)d_in[2];
  const float* K_b  = (const float*)d_in[3];
  const float* Q_W  = (const float*)d_in[4];
  const float* Q_b  = (const float*)d_in[5];
  const float* V_W  = (const float*)d_in[6];
  const float* V_b  = (const float*)d_in[7];
  const float* O_W  = (const float*)d_in[8];
  const float* O_b  = (const float*)d_in[9];
  const float* ln1g = (const float*)d_in[10];
  const float* ln1b = (const float*)d_in[11];
  const float* ln2g = (const float*)d_in[12];
  const float* ln2b = (const float*)d_in[13];
  const float* W1   = (const float*)d_in[14];
  const float* b1   = (const float*)d_in[15];
  const float* W2   = (const float*)d_in[16];
  const float* b2   = (const float*)d_in[17];
  float* out = (float*)d_out;

  unsigned char* ws = (unsigned char*)d_ws;
  const size_t MB = 1u << 20;
  float* bufx           = (float*)(ws);                      // xs fp32, 16MB
  unsigned short* qkh   = (unsigned short*)(ws + 16 * MB);   // (B,S,1024) 16MB
  unsigned short* qkl   = (unsigned short*)(ws + 32 * MB);   // 16MB
  unsigned short* vh    = (unsigned short*)(ws + 48 * MB);   // (B,S,512) 8MB
  unsigned short* ln1h  = (unsigned short*)(ws + 56 * MB);   // 8MB
  unsigned short* ln1l  = (unsigned short*)(ws + 64 * MB);   // 8MB
  unsigned short* oh    = ln1h;                              // reuse after QKV GEMM
  float* out1           = (float*)(ws + 72 * MB);            // 16MB fp32 residual
  unsigned short* ln2h  = (unsigned short*)(ws + 16 * MB);   // reuse qkh (dead post-attn)
  unsigned short* geluh = (unsigned short*)(ws + 24 * MB);   // reuse qkh 2nd half
  float* out2           = (float*)(ws + 32 * MB);            // reuse qkl, 16MB
  unsigned short* BtAll = (unsigned short*)(ws + 88 * MB);   // [QKh 1024 | Vh 512] x 512
  unsigned short* BtQKh = BtAll;
  unsigned short* BtVh  = BtAll + 1024 * 512;
  unsigned short* BtQKl = BtVh + 512 * 512;
  unsigned short* BtOh  = BtQKl + 1024 * 512;
  unsigned short* BtOl  = BtOh + 512 * 512;
  unsigned short* BtW1h = BtOl + 512 * 512;
  unsigned short* BtW2h = BtW1h + 512 * 512;
  float* qkvb           = (float*)(BtW2h + 512 * 512);

  dim3 tb32(32, 8);
  transpose_k<<<dim3(SS / 32, CC / 32, BB), tb32, 0, stream>>>(x, bufx, CC, SS);
  convert_weights<<<dim3(16, 2, 48), tb32, 0, stream>>>(
      Q_W, K_W, V_W, O_W, W1, W2, Q_b, K_b, V_b,
      BtQKh, BtQKl, BtVh, BtOh, BtOl, BtW1h, BtW2h, qkvb);
  ln_bf16_k<<<BB * SS, 256, 0, stream>>>(bufx, ln1g, ln1b, ln1h, ln1l);
  // fused QKV projection: QK split (hi+lo out), V plain (hi out)
  gemm_qkv<<<dim3(12, 64), 256, 0, stream>>>(
      ln1h, ln1l, BtAll, BtQKl, qkvb, qkh, qkl, vh);
  attn_mfma<<<dim3(SS / 64, NHH, BB), 256, 0, stream>>>(qkh, qkl, vh, oh);
  // O projection (B split) + residual(xs) -> out1 fp32
  gemm64<1, 0, 0, 1><<<dim3(8, 128), 256, 0, stream>>>(
      oh, BtOh, BtOl, O_b, bufx, nullptr, out1, CC);
  ln_bf16_k<<<BB * SS, 256, 0, stream>>>(out1, ln2g, ln2b, ln2h, nullptr);
  // MLP: W1 + exact GELU -> bf16
  gemm64<0, 1, 1, 0><<<dim3(8, 128), 256, 0, stream>>>(
      ln2h, BtW1h, nullptr, b1, nullptr, geluh, nullptr, CC);
  // W2 + residual(out1) -> fp32
  gemm64<0, 0, 0, 1><<<dim3(8, 128), 256, 0, stream>>>(
      geluh, BtW2h, nullptr, b2, out1, nullptr, out2, CC);
  transpose_k<<<dim3(CC / 32, SS / 32, BB), tb32, 0, stream>>>(out2, out, SS, CC);
}

// Round 6
// 301.678 us; speedup vs baseline: 3.3565x; 1.0670x over previous
//
#include <hip/hip_runtime.h>
#include <math.h>

#define BB 8
#define CC 512
#define SS 1024
#define NHH 8
#define HDD 64
#define KD 512

typedef __attribute__((ext_vector_type(8))) short short8;
typedef __attribute__((ext_vector_type(4))) float f32x4;

__device__ __forceinline__ unsigned short f2bf(float x) {
  union { float f; unsigned int u; } c; c.f = x;
  unsigned int r = (c.u + 0x7FFFu + ((c.u >> 16) & 1u)) >> 16;
  return (unsigned short)r;
}
__device__ __forceinline__ float b2f(unsigned short h) {
  union { unsigned int u; float f; } c; c.u = ((unsigned int)h) << 16; return c.f;
}

#define GLD_LDS(gp, lp) __builtin_amdgcn_global_load_lds( \
    (const __attribute__((address_space(1))) void*)(gp),  \
    (__attribute__((address_space(3))) void*)(lp), 16, 0, 0)

// ---------- block-wide sum over 256 threads (4 waves) ----------
__device__ __forceinline__ float block_reduce_sum(float v) {
  __shared__ float sm[4];
  #pragma unroll
  for (int o = 32; o > 0; o >>= 1) v += __shfl_down(v, o, 64);
  if ((threadIdx.x & 63) == 0) sm[threadIdx.x >> 6] = v;
  __syncthreads();
  float r = (sm[0] + sm[1]) + (sm[2] + sm[3]);
  __syncthreads();
  return r;
}

// ---------- batched 2D transpose: in (B, d1, d2) -> out (B, d2, d1), fp32 ----
__global__ __launch_bounds__(256) void transpose_k(const float* __restrict__ in,
                                                   float* __restrict__ out,
                                                   int d1, int d2) {
  __shared__ float tile[32][33];
  int b = blockIdx.z;
  int j0 = blockIdx.x * 32;
  int i0 = blockIdx.y * 32;
  const float* inb = in + (size_t)b * d1 * d2;
  float* outb = out + (size_t)b * d1 * d2;
  int tx = threadIdx.x, ty = threadIdx.y;  // (32, 8)
  #pragma unroll
  for (int i = ty; i < 32; i += 8)
    tile[i][tx] = inb[(size_t)(i0 + i) * d2 + j0 + tx];
  __syncthreads();
  #pragma unroll
  for (int i = ty; i < 32; i += 8)
    outb[(size_t)(j0 + i) * d1 + i0 + tx] = tile[tx][i];
}

// ---------- LayerNorm (C=512) -> bf16 hi (+ optional lo plane) ---------------
__global__ __launch_bounds__(256) void ln_bf16_k(const float* __restrict__ in,
                                                 const float* __restrict__ g,
                                                 const float* __restrict__ be,
                                                 unsigned short* __restrict__ outh,
                                                 unsigned short* __restrict__ outl) {
  size_t row = blockIdx.x;
  const float* r = in + row * CC;
  int t = threadIdx.x;
  float v0 = r[t], v1 = r[t + 256];
  float s = block_reduce_sum(v0 + v1);
  float mu = s * (1.0f / CC);
  float d0 = v0 - mu, d1 = v1 - mu;
  float vs = block_reduce_sum(d0 * d0 + d1 * d1);
  float rstd = rsqrtf(vs * (1.0f / CC) + 1e-5f);
  float y0 = d0 * rstd * g[t] + be[t];
  float y1 = d1 * rstd * g[t + 256] + be[t + 256];
  unsigned short h0 = f2bf(y0), h1 = f2bf(y1);
  outh[row * CC + t]       = h0;
  outh[row * CC + t + 256] = h1;
  if (outl) {
    outl[row * CC + t]       = f2bf(y0 - b2f(h0));
    outl[row * CC + t + 256] = f2bf(y1 - b2f(h1));
  }
}

// ---------- weight convert: fp32 -> bf16 hi/lo B^T (N,K) ---------------------
__global__ __launch_bounds__(256) void convert_weights(
    const float* __restrict__ QW, const float* __restrict__ KW,
    const float* __restrict__ VW, const float* __restrict__ OW,
    const float* __restrict__ W1, const float* __restrict__ W2,
    const float* __restrict__ Qb, const float* __restrict__ Kb,
    const float* __restrict__ Vb,
    unsigned short* __restrict__ BtQKh, unsigned short* __restrict__ BtQKl,
    unsigned short* __restrict__ BtVh,
    unsigned short* __restrict__ BtOh, unsigned short* __restrict__ BtOl,
    unsigned short* __restrict__ BtW1h, unsigned short* __restrict__ BtW2h,
    float* __restrict__ qkvb) {
  __shared__ float tile[32][33];
  const int p = blockIdx.z, wsel = p >> 3, sub = p & 7;
  const int k0 = blockIdx.x * 32, d0 = blockIdx.y * 32;
  const int tx = threadIdx.x, ty = threadIdx.y;
  const float* w; int rs; unsigned short *dh, *dl; int nbase;
  switch (wsel) {
    case 0:  w = QW + sub * 32768; rs = 64;  dh = BtQKh; dl = BtQKl;  nbase = sub * 64;        break;
    case 1:  w = KW + sub * 32768; rs = 64;  dh = BtQKh; dl = BtQKl;  nbase = 512 + sub * 64;  break;
    case 2:  w = VW + sub * 32768; rs = 64;  dh = BtVh;  dl = nullptr; nbase = sub * 64;       break;
    case 3:  w = OW + sub * 64;    rs = 512; dh = BtOh;  dl = BtOl;   nbase = sub * 64;        break;
    case 4:  w = W1 + sub * 64;    rs = 512; dh = BtW1h; dl = nullptr; nbase = sub * 64;       break;
    default: w = W2 + sub * 64;    rs = 512; dh = BtW2h; dl = nullptr; nbase = sub * 64;       break;
  }
  for (int i = ty; i < 32; i += 8)
    tile[i][tx] = w[(size_t)(k0 + i) * rs + d0 + tx];
  __syncthreads();
  for (int i = ty; i < 32; i += 8) {
    float f = tile[tx][i];
    unsigned short h = f2bf(f);
    size_t idx = (size_t)(nbase + d0 + i) * KD + k0 + tx;
    dh[idx] = h;
    if (dl) dl[idx] = f2bf(f - b2f(h));
  }
  if (p == 0 && blockIdx.x == 0 && blockIdx.y == 0) {
    int t = ty * 32 + tx;
    for (int i = t; i < 1536; i += 256)
      qkvb[i] = i < 512 ? Qb[i] : (i < 1024 ? Kb[i - 512] : Vb[i - 1024]);
  }
}

// ---------- fused QKV projection GEMM, 128x128 tiles, xor-swizzled LDS -------
__global__ __launch_bounds__(256) void gemm_qkv(
    const unsigned short* __restrict__ Ah, const unsigned short* __restrict__ Al,
    const unsigned short* __restrict__ Bth, const unsigned short* __restrict__ Btl,
    const float* __restrict__ bias,
    unsigned short* __restrict__ qkh, unsigned short* __restrict__ qkl,
    unsigned short* __restrict__ vh) {
  __shared__ __align__(16) unsigned short As[2 * 128 * 32];
  __shared__ __align__(16) unsigned short Bs[2 * 128 * 32];
  const int tid = threadIdx.x;
  const int w = tid >> 6, l = tid & 63, quad = l >> 4, lm = l & 15;
  const int n0 = blockIdx.x * 128, m0 = blockIdx.y * 128;
  const bool splitB = n0 < 1024;
  const int wm = (w >> 1) * 64, wn = (w & 1) * 64;
  const int srow = tid >> 2;
  const int sch = (((tid & 3) ^ (srow & 3)) * 8);  // xor-swizzled source chunk
  const unsigned short* Agh = Ah + (size_t)(m0 + srow) * KD + sch;
  const unsigned short* Agl = Al + (size_t)(m0 + srow) * KD + sch;
  const unsigned short* Bgh = Bth + (size_t)(n0 + srow) * KD + sch;
  const unsigned short* Bgl = Btl + (size_t)(n0 + srow) * KD + sch;
  unsigned short* Aswh = As + w * 512;
  unsigned short* Aswl = As + 4096 + w * 512;
  unsigned short* Bswh = Bs + w * 512;
  unsigned short* Bswl = Bs + 4096 + w * 512;
  const int rch = ((quad ^ (lm & 3)) * 8);  // swizzled read chunk
  const f32x4 fzero = {0.f, 0.f, 0.f, 0.f};
  f32x4 acc[4][4];
  #pragma unroll
  for (int i = 0; i < 4; ++i)
    #pragma unroll
    for (int j = 0; j < 4; ++j) acc[i][j] = fzero;
  for (int k0 = 0; k0 < KD; k0 += 32) {
    __syncthreads();
    GLD_LDS(Agh + k0, Aswh);
    GLD_LDS(Agh + k0 + 64 * KD, Aswh + 2048);
    GLD_LDS(Agl + k0, Aswl);
    GLD_LDS(Agl + k0 + 64 * KD, Aswl + 2048);
    GLD_LDS(Bgh + k0, Bswh);
    GLD_LDS(Bgh + k0 + 64 * KD, Bswh + 2048);
    if (splitB) {
      GLD_LDS(Bgl + k0, Bswl);
      GLD_LDS(Bgl + k0 + 64 * KD, Bswl + 2048);
    }
    __syncthreads();
    short8 afh[4], afl[4], bfh[4], bfl[4];
    #pragma unroll
    for (int i = 0; i < 4; ++i) {
      afh[i] = *(const short8*)(As + (wm + i * 16 + lm) * 32 + rch);
      afl[i] = *(const short8*)(As + 4096 + (wm + i * 16 + lm) * 32 + rch);
    }
    #pragma unroll
    for (int j = 0; j < 4; ++j)
      bfh[j] = *(const short8*)(Bs + (wn + j * 16 + lm) * 32 + rch);
    if (splitB) {
      #pragma unroll
      for (int j = 0; j < 4; ++j)
        bfl[j] = *(const short8*)(Bs + 4096 + (wn + j * 16 + lm) * 32 + rch);
      #pragma unroll
      for (int i = 0; i < 4; ++i)
        #pragma unroll
        for (int j = 0; j < 4; ++j) {
          f32x4 t = acc[i][j];
          t = __builtin_amdgcn_mfma_f32_16x16x32_bf16(afh[i], bfh[j], t, 0, 0, 0);
          t = __builtin_amdgcn_mfma_f32_16x16x32_bf16(afh[i], bfl[j], t, 0, 0, 0);
          t = __builtin_amdgcn_mfma_f32_16x16x32_bf16(afl[i], bfh[j], t, 0, 0, 0);
          acc[i][j] = t;
        }
    } else {
      #pragma unroll
      for (int i = 0; i < 4; ++i)
        #pragma unroll
        for (int j = 0; j < 4; ++j)
          acc[i][j] = __builtin_amdgcn_mfma_f32_16x16x32_bf16(afh[i], bfh[j], acc[i][j], 0, 0, 0);
    }
  }
  #pragma unroll
  for (int i = 0; i < 4; ++i) {
    const int row = m0 + wm + i * 16 + quad * 4;
    #pragma unroll
    for (int j = 0; j < 4; ++j) {
      const int ncol = n0 + wn + j * 16 + lm;
      const float bv = bias[ncol];
      #pragma unroll
      for (int r = 0; r < 4; ++r) {
        float x = acc[i][j][r] + bv;
        if (splitB) {
          const size_t oi = (size_t)(row + r) * 1024 + ncol;
          unsigned short h = f2bf(x);
          qkh[oi] = h;
          qkl[oi] = f2bf(x - b2f(h));
        } else {
          vh[(size_t)(row + r) * 512 + (ncol - 1024)] = f2bf(x);
        }
      }
    }
  }
}

// ---------- 64x64-tile GEMM, xor-swizzled; TRANS: write (B,C,S) via LDS ------
template<int SB, int GELU, int OUTMODE, int RESID, int TRANS>
__global__ __launch_bounds__(256) void gemm64(
    const unsigned short* __restrict__ Ah,
    const unsigned short* __restrict__ Bh, const unsigned short* __restrict__ Bl,
    const float* __restrict__ bias, const float* __restrict__ resid,
    unsigned short* __restrict__ outh, float* __restrict__ outf, int ldc) {
  __shared__ __align__(16) unsigned short As[64 * 32];
  __shared__ __align__(16) unsigned short Bs[(SB ? 2 : 1) * 64 * 32];
  __shared__ float ttile[TRANS ? 64 : 1][TRANS ? 65 : 1];
  const int tid = threadIdx.x;
  const int w = tid >> 6, l = tid & 63, quad = l >> 4, lm = l & 15;
  const int n0 = blockIdx.x * 64, m0 = blockIdx.y * 64;
  const int wm = (w >> 1) * 32, wn = (w & 1) * 32;
  const int srow = tid >> 2;
  const int sch = (((tid & 3) ^ (srow & 3)) * 8);
  const unsigned short* Ag = Ah + (size_t)(m0 + srow) * KD + sch;
  const unsigned short* Bg = Bh + (size_t)(n0 + srow) * KD + sch;
  const unsigned short* Bgl = SB ? Bl + (size_t)(n0 + srow) * KD + sch : nullptr;
  unsigned short* Asw = As + w * 512;
  unsigned short* Bsw = Bs + w * 512;
  unsigned short* Bswl = Bs + 2048 + w * 512;
  const int rch = ((quad ^ (lm & 3)) * 8);
  const f32x4 fzero = {0.f, 0.f, 0.f, 0.f};
  f32x4 acc[2][2];
  #pragma unroll
  for (int i = 0; i < 2; ++i)
    #pragma unroll
    for (int j = 0; j < 2; ++j) acc[i][j] = fzero;
  for (int k0 = 0; k0 < KD; k0 += 32) {
    __syncthreads();
    GLD_LDS(Ag + k0, Asw);
    GLD_LDS(Bg + k0, Bsw);
    if constexpr (SB) GLD_LDS(Bgl + k0, Bswl);
    __syncthreads();
    short8 af[2], bfh[2], bfl[2];
    #pragma unroll
    for (int i = 0; i < 2; ++i)
      af[i] = *(const short8*)(As + (wm + i * 16 + lm) * 32 + rch);
    #pragma unroll
    for (int j = 0; j < 2; ++j)
      bfh[j] = *(const short8*)(Bs + (wn + j * 16 + lm) * 32 + rch);
    if constexpr (SB) {
      #pragma unroll
      for (int j = 0; j < 2; ++j)
        bfl[j] = *(const short8*)(Bs + 2048 + (wn + j * 16 + lm) * 32 + rch);
    }
    #pragma unroll
    for (int i = 0; i < 2; ++i)
      #pragma unroll
      for (int j = 0; j < 2; ++j) {
        f32x4 t = acc[i][j];
        t = __builtin_amdgcn_mfma_f32_16x16x32_bf16(af[i], bfh[j], t, 0, 0, 0);
        if constexpr (SB)
          t = __builtin_amdgcn_mfma_f32_16x16x32_bf16(af[i], bfl[j], t, 0, 0, 0);
        acc[i][j] = t;
      }
  }
  if constexpr (TRANS) __syncthreads();  // protect ttile vs last As/Bs reads
  #pragma unroll
  for (int i = 0; i < 2; ++i) {
    const int row = m0 + wm + i * 16 + quad * 4;
    #pragma unroll
    for (int j = 0; j < 2; ++j) {
      const int col = n0 + wn + j * 16 + lm;
      const float bv = bias[col];
      #pragma unroll
      for (int r = 0; r < 4; ++r) {
        float x = acc[i][j][r] + bv;
        if (GELU) x = 0.5f * x * (1.0f + erff(x * 0.70710678118654752f));
        if (RESID) x += resid[(size_t)(row + r) * CC + col];
        if constexpr (TRANS) {
          ttile[wm + i * 16 + quad * 4 + r][wn + j * 16 + lm] = x;
        } else {
          const size_t oi = (size_t)(row + r) * ldc + col;
          if (OUTMODE == 0) outf[oi] = x;
          else outh[oi] = f2bf(x);
        }
      }
    }
  }
  if constexpr (TRANS) {
    __syncthreads();
    const int bi = m0 >> 10, s0 = m0 & 1023;
    const int s = tid & 63;
    #pragma unroll
    for (int c0 = 0; c0 < 64; c0 += 4) {
      const int col = c0 + (tid >> 6);
      outf[(size_t)(bi * 512 + n0 + col) * 1024 + s0 + s] = ttile[s][col];
    }
  }
}

// ---------- flash attention: GLD_LDS K staging, ones-column row-sum ----------
// QK hi/lo: (B, S, 1024) bf16 [Q | K]; V hi: (B, S, 512); O hi: (B, S, 512)
__global__ __launch_bounds__(256) void attn_mfma(
    const unsigned short* __restrict__ QKh, const unsigned short* __restrict__ QKl,
    const unsigned short* __restrict__ Vh, unsigned short* __restrict__ Oh) {
  __shared__ __align__(16) unsigned short Ksh[64 * 64], Ksl[64 * 64];  // xor-swizzled
  __shared__ __align__(16) unsigned short Vth[64 * 72];
  __shared__ __align__(16) unsigned short Ps[4 * 16 * 88];
  const int q0 = blockIdx.x * 64, h = blockIdx.y, b = blockIdx.z;
  const int tid = threadIdx.x, w = tid >> 6, l = tid & 63, quad = l >> 4, lm = l & 15;
  const int LDQ = 2 * CC;
  const size_t qkbase = (size_t)b * SS * LDQ;
  const size_t vbase  = (size_t)b * SS * CC;
  // K staging coords (GLD_LDS): 32 rows/instr, 8 chunks of 16B per 64-short row
  const int srow8 = tid >> 3;                            // 0..31
  const int sch8  = ((tid & 7) ^ (srow8 & 7)) * 8;       // xor-swizzled source chunk
  // Q fragments in registers (A-layout: m=lm, k=st*32+quad*8)
  short8 qh[2], ql[2];
  {
    const size_t qo = qkbase + (size_t)(q0 + w * 16 + lm) * LDQ + h * 64 + quad * 8;
    qh[0] = *(const short8*)(QKh + qo);
    qh[1] = *(const short8*)(QKh + qo + 32);
    ql[0] = *(const short8*)(QKl + qo);
    ql[1] = *(const short8*)(QKl + qo + 32);
  }
  // ones B-fragment: column n'=0 all-ones (row-sum via MFMA)
  short8 bones;
  #pragma unroll
  for (int u = 0; u < 8; ++u) bones[u] = (lm == 0) ? (short)0x3F80 : (short)0;
  const f32x4 fzero = {0.f, 0.f, 0.f, 0.f};
  float mrow[4];
  f32x4 oacc[5];  // [0..3]=O cols, [4]=row-sum (l) accumulator
  #pragma unroll
  for (int r = 0; r < 4; ++r) mrow[r] = -1e30f;
  #pragma unroll
  for (int j = 0; j < 5; ++j) oacc[j] = fzero;
  const float scale = 0.044194173824159216f;  // 1/sqrt(512)
  unsigned short* Pw = Ps + w * (16 * 88);
  for (int kt = 0; kt < SS; kt += 64) {
    __syncthreads();  // previous tile fully consumed
    {
      const unsigned short* kg  = QKh + qkbase + (size_t)(kt + srow8) * LDQ + CC + h * 64 + sch8;
      const unsigned short* kgl = QKl + qkbase + (size_t)(kt + srow8) * LDQ + CC + h * 64 + sch8;
      GLD_LDS(kg, Ksh + w * 512);
      GLD_LDS(kg + 32 * LDQ, Ksh + 2048 + w * 512);
      GLD_LDS(kgl, Ksl + w * 512);
      GLD_LDS(kgl + 32 * LDQ, Ksl + 2048 + w * 512);
      #pragma unroll
      for (int pass = 0; pass < 2; ++pass) {
        const int c = w + pass * 4;
        const size_t vo = vbase + (size_t)(kt + l) * CC + h * 64 + c * 8;
        short8 vh8 = *(const short8*)(Vh + vo);
        #pragma unroll
        for (int u = 0; u < 8; ++u) Vth[(c * 8 + u) * 72 + l] = (unsigned short)vh8[u];
      }
    }
    __syncthreads();  // tiles visible (drains GLD + V writes)
    // scores (bf16x3): wave w's 16 q-rows vs 64 keys
    f32x4 sc[4];
    #pragma unroll
    for (int j = 0; j < 4; ++j) sc[j] = fzero;
    #pragma unroll
    for (int st = 0; st < 2; ++st) {
      const int kc = ((st * 4 + quad) ^ (lm & 7)) * 8;  // swizzled chunk
      #pragma unroll
      for (int j = 0; j < 4; ++j) {
        short8 kh = *(const short8*)(Ksh + (j * 16 + lm) * 64 + kc);
        short8 kl = *(const short8*)(Ksl + (j * 16 + lm) * 64 + kc);
        f32x4 t = sc[j];
        t = __builtin_amdgcn_mfma_f32_16x16x32_bf16(qh[st], kh, t, 0, 0, 0);
        t = __builtin_amdgcn_mfma_f32_16x16x32_bf16(qh[st], kl, t, 0, 0, 0);
        t = __builtin_amdgcn_mfma_f32_16x16x32_bf16(ql[st], kh, t, 0, 0, 0);
        sc[j] = t;
      }
    }
    #pragma unroll
    for (int j = 0; j < 4; ++j) sc[j] *= scale;
    // online softmax: max-reduce only (sum comes from ones-column MFMA)
    #pragma unroll
    for (int r = 0; r < 4; ++r) {
      float mt = fmaxf(fmaxf(sc[0][r], sc[1][r]), fmaxf(sc[2][r], sc[3][r]));
      #pragma unroll
      for (int mask = 1; mask < 16; mask <<= 1) mt = fmaxf(mt, __shfl_xor(mt, mask, 64));
      const float mn = fmaxf(mrow[r], mt);
      const float alpha = __expf(mrow[r] - mn);
      mrow[r] = mn;
      #pragma unroll
      for (int j = 0; j < 4; ++j) sc[j][r] = __expf(sc[j][r] - mn);
      #pragma unroll
      for (int j = 0; j < 5; ++j) oacc[j][r] *= alpha;
    }
    // P -> per-wave LDS (A-layout); same-wave producer/consumer
    #pragma unroll
    for (int r = 0; r < 4; ++r)
      #pragma unroll
      for (int j = 0; j < 4; ++j)
        Pw[(quad * 4 + r) * 88 + j * 16 + lm] = f2bf(sc[j][r]);
    #pragma unroll
    for (int st = 0; st < 2; ++st) {
      short8 ap = *(const short8*)(Pw + lm * 88 + st * 32 + quad * 8);
      #pragma unroll
      for (int j = 0; j < 4; ++j) {
        short8 vv = *(const short8*)(Vth + (j * 16 + lm) * 72 + st * 32 + quad * 8);
        oacc[j] = __builtin_amdgcn_mfma_f32_16x16x32_bf16(ap, vv, oacc[j], 0, 0, 0);
      }
      oacc[4] = __builtin_amdgcn_mfma_f32_16x16x32_bf16(ap, bones, oacc[4], 0, 0, 0);
    }
  }
  float inv[4];
  #pragma unroll
  for (int r = 0; r < 4; ++r) {
    const float lv = __shfl(oacc[4][r], l & 48, 64);  // broadcast col 0 of quad
    inv[r] = 1.f / lv;
  }
  const size_t obase = vbase + (size_t)(q0 + w * 16 + quad * 4) * CC + h * 64 + lm;
  #pragma unroll
  for (int j = 0; j < 4; ++j)
    #pragma unroll
    for (int r = 0; r < 4; ++r)
      Oh[obase + (size_t)r * CC + j * 16] = f2bf(oacc[j][r] * inv[r]);
}

extern "C" void kernel_launch(void* const* d_in, const int* in_sizes, int n_in,
                              void* d_out, int out_size, void* d_ws, size_t ws_size,
                              hipStream_t stream) {
  const float* x    = (const float*)d_in[0];
  const float* K_W  = (const float*)d_in[2];
  const float* K_b  = (const float*)d_in[3];
  const float* Q_W  = (const float*)d_in[4];
  const float* Q_b  = (const float*)d_in[5];
  const float* V_W  = (const float*)d_in[6];
  const float* V_b  = (const float*)d_in[7];
  const float* O_W  = (const float*)d_in[8];
  const float* O_b  = (const float*)d_in[9];
  const float* ln1g = (const float*)d_in[10];
  const float* ln1b = (const float*)d_in[11];
  const float* ln2g = (const float*)d_in[12];
  const float* ln2b = (const float*)d_in[13];
  const float* W1   = (const float*)d_in[14];
  const float* b1   = (const float*)d_in[15];
  const float* W2   = (const float*)d_in[16];
  const float* b2   = (const float*)d_in[17];
  float* out = (float*)d_out;

  unsigned char* ws = (unsigned char*)d_ws;
  const size_t MB = 1u << 20;
  float* bufx           = (float*)(ws);                      // xs fp32, 16MB
  unsigned short* qkh   = (unsigned short*)(ws + 16 * MB);   // (B,S,1024) 16MB
  unsigned short* qkl   = (unsigned short*)(ws + 32 * MB);   // 16MB
  unsigned short* vh    = (unsigned short*)(ws + 48 * MB);   // (B,S,512) 8MB
  unsigned short* ln1h  = (unsigned short*)(ws + 56 * MB);   // 8MB
  unsigned short* ln1l  = (unsigned short*)(ws + 64 * MB);   // 8MB
  unsigned short* oh    = ln1h;                              // reuse after QKV GEMM
  float* out1           = (float*)(ws + 72 * MB);            // 16MB fp32 residual
  unsigned short* ln2h  = (unsigned short*)(ws + 16 * MB);   // reuse qkh (dead post-attn)
  unsigned short* geluh = (unsigned short*)(ws + 24 * MB);   // reuse qkh 2nd half
  unsigned short* BtAll = (unsigned short*)(ws + 88 * MB);   // [QKh 1024 | Vh 512] x 512
  unsigned short* BtQKh = BtAll;
  unsigned short* BtVh  = BtAll + 1024 * 512;
  unsigned short* BtQKl = BtVh + 512 * 512;
  unsigned short* BtOh  = BtQKl + 1024 * 512;
  unsigned short* BtOl  = BtOh + 512 * 512;
  unsigned short* BtW1h = BtOl + 512 * 512;
  unsigned short* BtW2h = BtW1h + 512 * 512;
  float* qkvb           = (float*)(BtW2h + 512 * 512);

  dim3 tb32(32, 8);
  transpose_k<<<dim3(SS / 32, CC / 32, BB), tb32, 0, stream>>>(x, bufx, CC, SS);
  convert_weights<<<dim3(16, 2, 48), tb32, 0, stream>>>(
      Q_W, K_W, V_W, O_W, W1, W2, Q_b, K_b, V_b,
      BtQKh, BtQKl, BtVh, BtOh, BtOl, BtW1h, BtW2h, qkvb);
  ln_bf16_k<<<BB * SS, 256, 0, stream>>>(bufx, ln1g, ln1b, ln1h, ln1l);
  // fused QKV projection: QK split (hi+lo out), V plain (hi out)
  gemm_qkv<<<dim3(12, 64), 256, 0, stream>>>(
      ln1h, ln1l, BtAll, BtQKl, qkvb, qkh, qkl, vh);
  attn_mfma<<<dim3(SS / 64, NHH, BB), 256, 0, stream>>>(qkh, qkl, vh, oh);
  // O projection (B split) + residual(xs) -> out1 fp32
  gemm64<1, 0, 0, 1, 0><<<dim3(8, 128), 256, 0, stream>>>(
      oh, BtOh, BtOl, O_b, bufx, nullptr, out1, CC);
  ln_bf16_k<<<BB * SS, 256, 0, stream>>>(out1, ln2g, ln2b, ln2h, nullptr);
  // MLP: W1 + exact GELU -> bf16
  gemm64<0, 1, 1, 0, 0><<<dim3(8, 128), 256, 0, stream>>>(
      ln2h, BtW1h, nullptr, b1, nullptr, geluh, nullptr, CC);
  // W2 + residual(out1) -> fp32, transposed epilogue writes (B,C,S) directly
  gemm64<0, 0, 0, 1, 1><<<dim3(8, 128), 256, 0, stream>>>(
      geluh, BtW2h, nullptr, b2, out1, nullptr, out, CC);
}